// Round 13
// baseline (528.777 us; speedup 1.0000x reference)
//
#include <hip/hip_runtime.h>
#include <hip/hip_bf16.h>
#include <cstdint>
#include <cstddef>

// Problem dims (compile-time)
constexpr int Bc = 8;
constexpr int Vc = 2048;   // S*T
constexpr int Pc = 512;
constexpr int Hc = 8;
constexpr int Lc = 2;
constexpr int ROWS_KV = Bc * Vc;   // 16384
constexpr int ROWS_AT = Bc * Pc;   // 4096

typedef __attribute__((ext_vector_type(8))) short bf16x8;   // 8 bf16 (4 VGPRs)
typedef __attribute__((ext_vector_type(4))) float f32x4;

static __device__ __forceinline__ unsigned short f2bf(float v) {
    __hip_bfloat16 h = __float2bfloat16(v);
    return *(unsigned short*)&h;
}
static __device__ __forceinline__ float bf2f(unsigned short u) {
    unsigned int x = ((unsigned int)u) << 16;
    return __uint_as_float(x);
}

// ---------------------------------------------------------------------------
// Prep: encoded fp32 -> bf16 (row-major [16384][256])
// ---------------------------------------------------------------------------
__global__ __launch_bounds__(256) void conv_x_kernel(
    const float* __restrict__ x, unsigned short* __restrict__ xb)
{
    const int i = blockIdx.x * 256 + threadIdx.x;   // 1 float4 per thread
    float4 v = ((const float4*)x)[i];
    ushort4 o;
    o.x = f2bf(v.x); o.y = f2bf(v.y); o.z = f2bf(v.z); o.w = f2bf(v.w);
    ((ushort4*)xb)[i] = o;
}

// ---------------------------------------------------------------------------
// Merged prep: all weight transposes [K x C] fp32 -> [C x 256] bf16.
// grid z: 0..31 W1 (per net), 32..63 W2, 64..95 W3 (C=32), 96..103 misc.
// misc slots: 0=ds_W 1=ffW1_0 2=ffW1_1 3=ffW2_0 4=ffW2_1 5=deW1 6=deW2 7=deW3(C=128)
// ---------------------------------------------------------------------------
__global__ __launch_bounds__(256) void transpose_all_kernel(
    const float* kW1, const float* vW1, const float* kW2, const float* vW2,
    const float* kW3, const float* vW3,
    const float* ds_W, const float* ff_W1, const float* ff_W2,
    const float* de_W1, const float* de_W2, const float* de_W3,
    unsigned short* __restrict__ W1t, unsigned short* __restrict__ W2t,
    unsigned short* __restrict__ W3t, unsigned short* __restrict__ Wm)
{
    const int z = blockIdx.z;
    const float* src;
    unsigned short* dst;
    int C;
    if (z < 32) {
        const int net = z;
        src = ((net >> 4) ? vW1 : kW1) + (size_t)(net & 15) * 257 * 256;
        dst = W1t + (size_t)net * 65536;
        C = 256;
    } else if (z < 64) {
        const int net = z - 32;
        src = ((net >> 4) ? vW2 : kW2) + (size_t)(net & 15) * 256 * 256;
        dst = W2t + (size_t)net * 65536;
        C = 256;
    } else if (z < 96) {
        const int net = z - 64;
        src = ((net >> 4) ? vW3 : kW3) + (size_t)(net & 15) * 256 * 32;
        dst = W3t + (size_t)net * 8192;
        C = 32;
    } else {
        const int id = z - 96;
        const float* srcs[8] = {ds_W, ff_W1, ff_W1 + (size_t)65536,
                                ff_W2, ff_W2 + (size_t)65536, de_W1, de_W2, de_W3};
        src = srcs[id];
        dst = Wm + (size_t)id * 65536;
        C = (id == 7) ? 128 : 256;
    }
    if (blockIdx.x * 32 >= C) return;
    __shared__ float t[32][33];
    const int c0 = blockIdx.x * 32, k0 = blockIdx.y * 32;
    const int tx = threadIdx.x & 31, ty = threadIdx.x >> 5;
    #pragma unroll
    for (int i = 0; i < 32; i += 8)
        t[ty + i][tx] = src[(size_t)(k0 + ty + i) * C + (c0 + tx)];
    __syncthreads();
    #pragma unroll
    for (int i = 0; i < 32; i += 8)
        dst[(size_t)(c0 + ty + i) * 256 + (k0 + tx)] = f2bf(t[tx][ty + i]);
}

// h-buf XOR swizzle: rows x 256 shorts (32 chunks of 8 shorts).
// chunk c of row r stored at p = c ^ (r & 31).
static __device__ __forceinline__ int hsw_chunk(int row, int ks, int quad) {
    int c = ks * 4 + quad;
    int p = c ^ (row & 31);
    return row * 256 + p * 8;
}
static __device__ __forceinline__ int hsw_elem(int row, int col) {
    int p = (col >> 3) ^ (row & 31);
    return row * 256 + p * 8 + (col & 7);
}

// ---------------------------------------------------------------------------
// Fused 3-layer KV MLP — v7c: weight-resident (W1/W2/W3 all in registers),
// 8 waves, 512 blocks.  Output bf16 [l][b][v][h*32].
// ---------------------------------------------------------------------------
__global__ __launch_bounds__(512, 2) void kv_mfma_kernel(
    const unsigned short* __restrict__ Xbf, const float* __restrict__ true_u,
    const unsigned short* __restrict__ W1t, const unsigned short* __restrict__ W2t,
    const unsigned short* __restrict__ W3t,
    const float* __restrict__ kW1, const float* __restrict__ vW1,
    const float* __restrict__ kb1, const float* __restrict__ kb2, const float* __restrict__ kb3,
    const float* __restrict__ vb1, const float* __restrict__ vb2, const float* __restrict__ vb3,
    unsigned short* __restrict__ keys, unsigned short* __restrict__ vals)
{
    __shared__ unsigned short hbuf[64 * 256];    // 32 KB: X -> h1 -> h2 (swizzled)
    __shared__ float tub[64];                    // true_u tile

    const int tid = threadIdx.x;
    const int w = tid >> 6, lane = tid & 63;
    const int ln = lane & 15, quad = lane >> 4;
    const int lh = blockIdx.y, isv = blockIdx.z;
    const int net = isv * 16 + lh;
    const float* W1f = (isv ? vW1 : kW1) + (size_t)lh * 257 * 256;
    const float* b1  = (isv ? vb1 : kb1) + lh * 256;
    const float* b2  = (isv ? vb2 : kb2) + lh * 256;
    const float* b3  = (isv ? vb3 : kb3) + lh * 32;
    const unsigned short* w1 = W1t + (size_t)net * 65536;
    const unsigned short* w2 = W2t + (size_t)net * 65536;
    const unsigned short* w3 = W3t + (size_t)net * 8192;
    unsigned short* outp = isv ? vals : keys;
    const int base = blockIdx.x * 1024;          // row-group (16 tiles)
    const int cb = w * 32;                       // wave's column base (stages 1-2)

    // ---- one-time: W1/W2 column slices -> registers (32 x 16B loads each) ----
    bf16x8 B1[16], B2[16];
    {
        const unsigned short* p1 = w1 + (size_t)(cb + ln) * 256 + quad * 8;
        const unsigned short* p2 = w2 + (size_t)(cb + ln) * 256 + quad * 8;
        #pragma unroll
        for (int ks = 0; ks < 8; ++ks)
            #pragma unroll
            for (int ct = 0; ct < 2; ++ct) {
                B1[ks * 2 + ct] = *(const bf16x8*)(p1 + (size_t)ct * 16 * 256 + ks * 32);
                B2[ks * 2 + ct] = *(const bf16x8*)(p2 + (size_t)ct * 16 * 256 + ks * 32);
            }
    }
    const int rt3 = w & 3, ct3 = w >> 2;         // stage-3 tile of this wave
    // ---- one-time: stage-3 W3 fragments -> registers (tile-invariant) ----
    bf16x8 B3[8];
    {
        const unsigned short* p3 = w3 + (size_t)(ct3 * 16 + ln) * 256 + quad * 8;
        #pragma unroll
        for (int ks = 0; ks < 8; ++ks)
            B3[ks] = *(const bf16x8*)(p3 + ks * 32);
    }
    // ---- one-time: per-lane epilogue constants ----
    float w1f[2], b1v[2], b2v[2];
    #pragma unroll
    for (int ct = 0; ct < 2; ++ct) {
        const int col = cb + ct * 16 + ln;
        w1f[ct] = W1f[256 * 256 + col];
        b1v[ct] = b1[col];
        b2v[ct] = b2[col];
    }
    const float b3v = b3[ct3 * 16 + ln];

    const int b_ = base >> 11;
    const int l_ = lh >> 3, h_ = lh & 7;
    // layout: [l][b][v][h*32 + col]
    unsigned short* ob = outp + (((size_t)l_ * Bc + b_) * Vc) * 256 + h_ * 32;

    const f32x4 zero = {0.f, 0.f, 0.f, 0.f};
    const int xr = tid >> 3, cg = tid & 7;       // X staging: 8 threads/row

    for (int t = 0; t < 16; ++t) {
        const int row0 = base + t * 64;
        __syncthreads();   // prior tile's stage-3 reads complete before X overwrite

        // ---- stage X tile + true_u into LDS ----
        {
            const unsigned short* gx = Xbf + (size_t)(row0 + xr) * 256;
            #pragma unroll
            for (int j = 0; j < 4; ++j) {
                const int c = j * 8 + cg;
                uint4 d = *(const uint4*)(gx + c * 8);
                *(uint4*)&hbuf[xr * 256 + (c ^ (xr & 31)) * 8] = d;
            }
            if (tid < 64) tub[tid] = true_u[row0 + tid];
        }
        __syncthreads();

        // ---- stage 1: h1 = relu(X @ W1 + tu*W1row256 + b1) ----
        f32x4 acc[4][2];
        #pragma unroll
        for (int rt = 0; rt < 4; ++rt)
            #pragma unroll
            for (int ct = 0; ct < 2; ++ct) acc[rt][ct] = zero;
        #pragma unroll
        for (int ks = 0; ks < 8; ++ks) {
            bf16x8 A[4];
            #pragma unroll
            for (int rt = 0; rt < 4; ++rt)
                A[rt] = *(const bf16x8*)&hbuf[hsw_chunk(rt * 16 + ln, ks, quad)];
            #pragma unroll
            for (int rt = 0; rt < 4; ++rt)
                #pragma unroll
                for (int ct = 0; ct < 2; ++ct)
                    acc[rt][ct] = __builtin_amdgcn_mfma_f32_16x16x32_bf16(A[rt], B1[ks * 2 + ct], acc[rt][ct], 0, 0, 0);
        }
        __syncthreads();   // all X reads done before h1 overwrite
        #pragma unroll
        for (int ct = 0; ct < 2; ++ct) {
            const int col = cb + ct * 16 + ln;
            #pragma unroll
            for (int rt = 0; rt < 4; ++rt)
                #pragma unroll
                for (int r = 0; r < 4; ++r) {
                    const int row = rt * 16 + quad * 4 + r;
                    float v = fmaxf(acc[rt][ct][r] + b1v[ct] + tub[row] * w1f[ct], 0.f);
                    hbuf[hsw_elem(row, col)] = f2bf(v);
                }
        }
        __syncthreads();

        // ---- stage 2: h2 = relu(h1 @ W2 + b2) ----
        #pragma unroll
        for (int rt = 0; rt < 4; ++rt)
            #pragma unroll
            for (int ct = 0; ct < 2; ++ct) acc[rt][ct] = zero;
        #pragma unroll
        for (int ks = 0; ks < 8; ++ks) {
            bf16x8 A[4];
            #pragma unroll
            for (int rt = 0; rt < 4; ++rt)
                A[rt] = *(const bf16x8*)&hbuf[hsw_chunk(rt * 16 + ln, ks, quad)];
            #pragma unroll
            for (int rt = 0; rt < 4; ++rt)
                #pragma unroll
                for (int ct = 0; ct < 2; ++ct)
                    acc[rt][ct] = __builtin_amdgcn_mfma_f32_16x16x32_bf16(A[rt], B2[ks * 2 + ct], acc[rt][ct], 0, 0, 0);
        }
        __syncthreads();   // all h1 reads done before h2 overwrite
        #pragma unroll
        for (int ct = 0; ct < 2; ++ct) {
            const int col = cb + ct * 16 + ln;
            #pragma unroll
            for (int rt = 0; rt < 4; ++rt)
                #pragma unroll
                for (int r = 0; r < 4; ++r) {
                    const int row = rt * 16 + quad * 4 + r;
                    hbuf[hsw_elem(row, col)] = f2bf(fmaxf(acc[rt][ct][r] + b2v[ct], 0.f));
                }
        }
        __syncthreads();

        // ---- stage 3: out = h2 @ W3 + b3; wave w -> 16x16 tile (rt3, ct3) ----
        f32x4 acc3 = zero;
        #pragma unroll
        for (int ks = 0; ks < 8; ++ks) {
            bf16x8 A = *(const bf16x8*)&hbuf[hsw_chunk(rt3 * 16 + ln, ks, quad)];
            acc3 = __builtin_amdgcn_mfma_f32_16x16x32_bf16(A, B3[ks], acc3, 0, 0, 0);
        }
        #pragma unroll
        for (int r = 0; r < 4; ++r) {
            const int grow = row0 + rt3 * 16 + quad * 4 + r;
            ob[(size_t)(grow & 2047) * 256 + ct3 * 16 + ln] = f2bf(acc3[r] + b3v);
        }
    }
}

// ---------------------------------------------------------------------------
// ds GEMM: AV[4096 x 256] = Xbf[gathered rows] @ ds_Wt^T + ds_b  (fp32 out)
// ---------------------------------------------------------------------------
__global__ __launch_bounds__(256) void ds_gemm_kernel(
    const unsigned short* __restrict__ Abf, const unsigned short* __restrict__ Wt,
    const float* __restrict__ bias, float* __restrict__ outF,
    const int* __restrict__ pp)
{
    const int tid = threadIdx.x;
    const int w = tid >> 6, lane = tid & 63;
    const int ln = lane & 15, quad = lane >> 4;
    const int row0 = blockIdx.x * 32;
    const int cb = w * 64;

    const f32x4 zero = {0.f, 0.f, 0.f, 0.f};
    f32x4 acc[2][4];
    #pragma unroll
    for (int rt = 0; rt < 2; ++rt)
        #pragma unroll
        for (int ct = 0; ct < 4; ++ct) acc[rt][ct] = zero;

    size_t arow[2];
    #pragma unroll
    for (int rt = 0; rt < 2; ++rt) {
        int ra = row0 + rt * 16 + ln;
        arow[rt] = (size_t)(ra >> 9) * Vc + pp[ra & 511];
    }
    const unsigned short* wb = Wt + (size_t)(cb + ln) * 256 + quad * 8;
    #pragma unroll
    for (int ks = 0; ks < 8; ++ks) {
        bf16x8 A[2], Bv[4];
        #pragma unroll
        for (int rt = 0; rt < 2; ++rt)
            A[rt] = *(const bf16x8*)(Abf + arow[rt] * 256 + ks * 32 + quad * 8);
        #pragma unroll
        for (int ct = 0; ct < 4; ++ct)
            Bv[ct] = *(const bf16x8*)(wb + (size_t)ct * 16 * 256 + ks * 32);
        #pragma unroll
        for (int rt = 0; rt < 2; ++rt)
            #pragma unroll
            for (int ct = 0; ct < 4; ++ct)
                acc[rt][ct] = __builtin_amdgcn_mfma_f32_16x16x32_bf16(A[rt], Bv[ct], acc[rt][ct], 0, 0, 0);
    }
    #pragma unroll
    for (int ct = 0; ct < 4; ++ct) {
        const int col = cb + ct * 16 + ln;
        const float bb = bias[col];
        #pragma unroll
        for (int rt = 0; rt < 2; ++rt)
            #pragma unroll
            for (int r = 0; r < 4; ++r)
                outF[(size_t)(row0 + rt * 16 + quad * 4 + r) * 256 + col] = acc[rt][ct][r] + bb;
    }
}

// ---------------------------------------------------------------------------
// Fused attention + residual + LayerNorm1 for one layer.
// blockIdx swizzled so XCD x (≈ blockIdx%8) handles batch x only: its 2MB
// K+V slice stays L2-resident (4MB/XCD).
// ---------------------------------------------------------------------------
__global__ __launch_bounds__(512) void attn_ln_kernel(
    const unsigned short* __restrict__ keys, const unsigned short* __restrict__ vals,
    const int* __restrict__ nbr, const float* __restrict__ mask,
    const float* __restrict__ g, const float* __restrict__ be,
    float* __restrict__ AV, unsigned short* __restrict__ AVbf, const int l)
{
    __shared__ float qs[256];
    __shared__ float wts[8 * 64];
    __shared__ float att_s[256];
    __shared__ int ni[64];
    __shared__ float red[4], red2[4];

    const int bid = blockIdx.x;
    const int row = ((bid & 7) << 9) | (bid >> 3);   // b = bid&7, p = bid>>3
    const int b = row >> 9, p = row & 511;
    const int tid = threadIdx.x;
    const int h = tid >> 6, n = tid & 63;

    if (tid < 256) qs[tid] = AV[(size_t)row * 256 + tid];
    if (tid < 64)  ni[tid] = nbr[p * 64 + tid];
    __syncthreads();

    const unsigned short* kvbase = keys + (((size_t)l * Bc + b) * Vc) * 256;
    const unsigned short* vvbase = vals + (((size_t)l * Bc + b) * Vc) * 256;

    // phase 1: scores + softmax (per head-wave)
    {
        const int vi = ni[n];
        const unsigned short* kp = kvbase + (size_t)vi * 256 + h * 32;
        const float* qh = qs + h * 32;
        float s = 0.f;
        #pragma unroll
        for (int j = 0; j < 4; ++j) {
            uint4 u = *(const uint4*)(kp + j * 8);
            const float* q = qh + j * 8;
            s += q[0] * __uint_as_float(u.x << 16) + q[1] * __uint_as_float(u.x & 0xffff0000u);
            s += q[2] * __uint_as_float(u.y << 16) + q[3] * __uint_as_float(u.y & 0xffff0000u);
            s += q[4] * __uint_as_float(u.z << 16) + q[5] * __uint_as_float(u.z & 0xffff0000u);
            s += q[6] * __uint_as_float(u.w << 16) + q[7] * __uint_as_float(u.w & 0xffff0000u);
        }
        s = (s - mask[p * 64 + n]) * 0.17677669529663689f;  // AD^-0.5
        float mx = s;
        #pragma unroll
        for (int off = 32; off >= 1; off >>= 1) mx = fmaxf(mx, __shfl_xor(mx, off));
        float e = expf(s - mx);
        float sum = e;
        #pragma unroll
        for (int off = 32; off >= 1; off >>= 1) sum += __shfl_xor(sum, off);
        wts[h * 64 + n] = e / sum;   // same-wave producer/consumer, no barrier
    }

    // phase 2: PV with all 64 lanes: lane = half*32 + d
    {
        const int d = n & 31, half = n >> 5;
        const float* wh = wts + h * 64 + half * 32;
        const int* nih = ni + half * 32;
        float a = 0.f;
        #pragma unroll 4
        for (int nn = 0; nn < 32; ++nn)
            a += wh[nn] * bf2f(vvbase[(size_t)nih[nn] * 256 + h * 32 + d]);
        a += __shfl_xor(a, 32);
        if (half == 0) att_s[h * 32 + d] = a;
    }
    __syncthreads();

    // phase 3: LN(AV + att) over 256 (first 4 waves carry data)
    float x = 0.f;
    if (tid < 256) x = qs[tid] + att_s[tid];
    float s = x;
    #pragma unroll
    for (int off = 32; off >= 1; off >>= 1) s += __shfl_xor(s, off);
    if ((tid & 63) == 0 && tid < 256) red[tid >> 6] = s;
    __syncthreads();
    const float mu = (red[0] + red[1] + red[2] + red[3]) * (1.0f / 256.0f);
    const float dx = x - mu;
    float v = dx * dx;
    #pragma unroll
    for (int off = 32; off >= 1; off >>= 1) v += __shfl_xor(v, off);
    if ((tid & 63) == 0 && tid < 256) red2[tid >> 6] = v;
    __syncthreads();
    if (tid < 256) {
        const float var = (red2[0] + red2[1] + red2[2] + red2[3]) * (1.0f / 256.0f);
        float o = dx * (1.0f / sqrtf(var + 1e-5f)) * g[tid] + be[tid];
        AV[(size_t)row * 256 + tid] = o;
        AVbf[(size_t)row * 256 + tid] = f2bf(o);
    }
}

// ---------------------------------------------------------------------------
// Fused FF block: AV = LN2(AV + relu(AVbf@W1+b1)@W2 + b2)  -> AV fp32 + AVbf.
// ---------------------------------------------------------------------------
__global__ __launch_bounds__(256) void ff_fused_kernel(
    const unsigned short* __restrict__ Abf, const float* __restrict__ resF,
    const unsigned short* __restrict__ W1t, const float* __restrict__ b1,
    const unsigned short* __restrict__ W2t, const float* __restrict__ b2,
    const float* __restrict__ g, const float* __restrict__ be,
    float* __restrict__ outF, unsigned short* __restrict__ outB)
{
    __shared__ unsigned short hbuf[32 * 256];   // 16 KB
    __shared__ float psum[32][4], psq[32][4];

    const int tid = threadIdx.x;
    const int w = tid >> 6, lane = tid & 63;
    const int ln = lane & 15, quad = lane >> 4;
    const int row0 = blockIdx.x * 32;
    const int cb = w * 64;

    const f32x4 zero = {0.f, 0.f, 0.f, 0.f};
    f32x4 acc[2][4];

    // ---- stage A: T1 = relu(A@W1 + b1) -> hbuf ----
    #pragma unroll
    for (int rt = 0; rt < 2; ++rt)
        #pragma unroll
        for (int ct = 0; ct < 4; ++ct) acc[rt][ct] = zero;
    {
        const unsigned short* ab = Abf + ((size_t)row0 + ln) * 256 + quad * 8;
        const unsigned short* wb = W1t + (size_t)(cb + ln) * 256 + quad * 8;
        #pragma unroll
        for (int ks = 0; ks < 8; ++ks) {
            bf16x8 A[2], Bv[4];
            #pragma unroll
            for (int rt = 0; rt < 2; ++rt)
                A[rt] = *(const bf16x8*)(ab + (size_t)rt * 16 * 256 + ks * 32);
            #pragma unroll
            for (int ct = 0; ct < 4; ++ct)
                Bv[ct] = *(const bf16x8*)(wb + (size_t)ct * 16 * 256 + ks * 32);
            #pragma unroll
            for (int rt = 0; rt < 2; ++rt)
                #pragma unroll
                for (int ct = 0; ct < 4; ++ct)
                    acc[rt][ct] = __builtin_amdgcn_mfma_f32_16x16x32_bf16(A[rt], Bv[ct], acc[rt][ct], 0, 0, 0);
        }
    }
    #pragma unroll
    for (int ct = 0; ct < 4; ++ct) {
        const int col = cb + ct * 16 + ln;
        const float bb = b1[col];
        #pragma unroll
        for (int rt = 0; rt < 2; ++rt)
            #pragma unroll
            for (int r = 0; r < 4; ++r) {
                const int row = rt * 16 + quad * 4 + r;
                hbuf[hsw_elem(row, col)] = f2bf(fmaxf(acc[rt][ct][r] + bb, 0.f));
            }
    }
    __syncthreads();

    // ---- stage B: T2 = T1@W2 + b2 (+ residual) ----
    #pragma unroll
    for (int rt = 0; rt < 2; ++rt)
        #pragma unroll
        for (int ct = 0; ct < 4; ++ct) acc[rt][ct] = zero;
    {
        const unsigned short* wb = W2t + (size_t)(cb + ln) * 256 + quad * 8;
        #pragma unroll
        for (int ks = 0; ks < 8; ++ks) {
            bf16x8 A[2], Bv[4];
            #pragma unroll
            for (int rt = 0; rt < 2; ++rt)
                A[rt] = *(const bf16x8*)&hbuf[hsw_chunk(rt * 16 + ln, ks, quad)];
            #pragma unroll
            for (int ct = 0; ct < 4; ++ct)
                Bv[ct] = *(const bf16x8*)(wb + (size_t)ct * 16 * 256 + ks * 32);
            #pragma unroll
            for (int rt = 0; rt < 2; ++rt)
                #pragma unroll
                for (int ct = 0; ct < 4; ++ct)
                    acc[rt][ct] = __builtin_amdgcn_mfma_f32_16x16x32_bf16(A[rt], Bv[ct], acc[rt][ct], 0, 0, 0);
        }
    }
    // v = T2 + b2 + residual; per-wave partial sums for LN
    float vv[2][4][4];
    #pragma unroll
    for (int ct = 0; ct < 4; ++ct) {
        const int col = cb + ct * 16 + ln;
        const float bb = b2[col];
        #pragma unroll
        for (int rt = 0; rt < 2; ++rt)
            #pragma unroll
            for (int r = 0; r < 4; ++r) {
                const int row = rt * 16 + quad * 4 + r;
                float res = resF[(size_t)(row0 + row) * 256 + col];
                vv[rt][ct][r] = acc[rt][ct][r] + bb + res;
            }
    }
    #pragma unroll
    for (int rt = 0; rt < 2; ++rt)
        #pragma unroll
        for (int r = 0; r < 4; ++r) {
            float sl = 0.f, ql = 0.f;
            #pragma unroll
            for (int ct = 0; ct < 4; ++ct) { float t = vv[rt][ct][r]; sl += t; ql += t * t; }
            #pragma unroll
            for (int off = 8; off >= 1; off >>= 1) {
                sl += __shfl_xor(sl, off);
                ql += __shfl_xor(ql, off);
            }
            if (ln == 0) {
                const int row = rt * 16 + quad * 4 + r;
                psum[row][w] = sl; psq[row][w] = ql;
            }
        }
    __syncthreads();

    // ---- LN epilogue ----
    #pragma unroll
    for (int rt = 0; rt < 2; ++rt)
        #pragma unroll
        for (int r = 0; r < 4; ++r) {
            const int row = rt * 16 + quad * 4 + r;
            const float mu = (psum[row][0] + psum[row][1] + psum[row][2] + psum[row][3]) * (1.0f / 256.0f);
            const float eq = (psq[row][0] + psq[row][1] + psq[row][2] + psq[row][3]) * (1.0f / 256.0f);
            const float rstd = 1.0f / sqrtf(fmaxf(eq - mu * mu, 0.f) + 1e-5f);
            #pragma unroll
            for (int ct = 0; ct < 4; ++ct) {
                const int col = cb + ct * 16 + ln;
                float o = (vv[rt][ct][r] - mu) * rstd * g[col] + be[col];
                outF[(size_t)(row0 + row) * 256 + col] = o;
                outB[(size_t)(row0 + row) * 256 + col] = f2bf(o);
            }
        }
}

// ---------------------------------------------------------------------------
// Fused decoder + loss
// ---------------------------------------------------------------------------
__global__ __launch_bounds__(256) void de_loss_kernel(
    const unsigned short* __restrict__ Abf,
    const unsigned short* __restrict__ W1t, const float* __restrict__ b1,
    const unsigned short* __restrict__ W2t, const float* __restrict__ b2,
    const unsigned short* __restrict__ W3t, const float* __restrict__ b3,
    const float* __restrict__ true_u, const int* __restrict__ pp,
    float* __restrict__ outp)
{
    __shared__ unsigned short hbuf[32 * 256];   // 16 KB
    __shared__ float pmax[32][4], psum[32][4], pxt[32][4];
    __shared__ float rowmax[32];
    __shared__ int tcol[32];

    const int tid = threadIdx.x;
    const int w = tid >> 6, lane = tid & 63;
    const int ln = lane & 15, quad = lane >> 4;
    const int row0 = blockIdx.x * 32;
    const int b = row0 >> 9;

    const f32x4 zero = {0.f, 0.f, 0.f, 0.f};
    f32x4 acc[2][4];

    // ---- stage 1: h1 ----
    #pragma unroll
    for (int rt = 0; rt < 2; ++rt)
        #pragma unroll
        for (int ct = 0; ct < 4; ++ct) acc[rt][ct] = zero;
    {
        const unsigned short* ab = Abf + ((size_t)row0 + ln) * 256 + quad * 8;
        const unsigned short* wb = W1t + (size_t)(w * 64 + ln) * 256 + quad * 8;
        #pragma unroll
        for (int ks = 0; ks < 8; ++ks) {
            bf16x8 A[2], Bv[4];
            #pragma unroll
            for (int rt = 0; rt < 2; ++rt)
                A[rt] = *(const bf16x8*)(ab + (size_t)rt * 16 * 256 + ks * 32);
            #pragma unroll
            for (int ct = 0; ct < 4; ++ct)
                Bv[ct] = *(const bf16x8*)(wb + (size_t)ct * 16 * 256 + ks * 32);
            #pragma unroll
            for (int rt = 0; rt < 2; ++rt)
                #pragma unroll
                for (int ct = 0; ct < 4; ++ct)
                    acc[rt][ct] = __builtin_amdgcn_mfma_f32_16x16x32_bf16(A[rt], Bv[ct], acc[rt][ct], 0, 0, 0);
        }
    }
    #pragma unroll
    for (int ct = 0; ct < 4; ++ct) {
        const int col = w * 64 + ct * 16 + ln;
        const float bb = b1[col];
        #pragma unroll
        for (int rt = 0; rt < 2; ++rt)
            #pragma unroll
            for (int r = 0; r < 4; ++r) {
                const int row = rt * 16 + quad * 4 + r;
                hbuf[hsw_elem(row, col)] = f2bf(fmaxf(acc[rt][ct][r] + bb, 0.f));
            }
    }
    __syncthreads();

    // ---- stage 2: h2 ----
    #pragma unroll
    for (int rt = 0; rt < 2; ++rt)
        #pragma unroll
        for (int ct = 0; ct < 4; ++ct) acc[rt][ct] = zero;
    {
        const unsigned short* wb = W2t + (size_t)(w * 64 + ln) * 256 + quad * 8;
        #pragma unroll
        for (int ks = 0; ks < 8; ++ks) {
            bf16x8 A[2], Bv[4];
            #pragma unroll
            for (int rt = 0; rt < 2; ++rt)
                A[rt] = *(const bf16x8*)&hbuf[hsw_chunk(rt * 16 + ln, ks, quad)];
            #pragma unroll
            for (int ct = 0; ct < 4; ++ct)
                Bv[ct] = *(const bf16x8*)(wb + (size_t)ct * 16 * 256 + ks * 32);
            #pragma unroll
            for (int rt = 0; rt < 2; ++rt)
                #pragma unroll
                for (int ct = 0; ct < 4; ++ct)
                    acc[rt][ct] = __builtin_amdgcn_mfma_f32_16x16x32_bf16(A[rt], Bv[ct], acc[rt][ct], 0, 0, 0);
        }
    }
    __syncthreads();
    #pragma unroll
    for (int ct = 0; ct < 4; ++ct) {
        const int col = w * 64 + ct * 16 + ln;
        const float bb = b2[col];
        #pragma unroll
        for (int rt = 0; rt < 2; ++rt)
            #pragma unroll
            for (int r = 0; r < 4; ++r) {
                const int row = rt * 16 + quad * 4 + r;
                hbuf[hsw_elem(row, col)] = f2bf(fmaxf(acc[rt][ct][r] + bb, 0.f));
            }
    }
    __syncthreads();

    // ---- stage 3: logits (128 cols; wave w -> cols w*32..+31) ----
    const int cb3 = w * 32;
    f32x4 a3[2][2];
    a3[0][0] = zero; a3[0][1] = zero; a3[1][0] = zero; a3[1][1] = zero;
    #pragma unroll
    for (int ks = 0; ks < 8; ++ks) {
        bf16x8 A[2];
        #pragma unroll
        for (int rt = 0; rt < 2; ++rt)
            A[rt] = *(const bf16x8*)&hbuf[hsw_chunk(rt * 16 + ln, ks, quad)];
        #pragma unroll
        for (int ct = 0; ct < 2; ++ct) {
            bf16x8 Bv = *(const bf16x8*)(W3t + (size_t)(cb3 + ct * 16 + ln) * 256 + ks * 32 + quad * 8);
            #pragma unroll
            for (int rt = 0; rt < 2; ++rt)
                a3[rt][ct] = __builtin_amdgcn_mfma_f32_16x16x32_bf16(A[rt], Bv, a3[rt][ct], 0, 0, 0);
        }
    }
    float lg[2][2][4];
    #pragma unroll
    for (int ct = 0; ct < 2; ++ct) {
        const float bb = b3[cb3 + ct * 16 + ln];
        #pragma unroll
        for (int rt = 0; rt < 2; ++rt)
            #pragma unroll
            for (int r = 0; r < 4; ++r) lg[rt][ct][r] = a3[rt][ct][r] + bb;
    }

    // per-wave row-max partials
    #pragma unroll
    for (int rt = 0; rt < 2; ++rt)
        #pragma unroll
        for (int r = 0; r < 4; ++r) {
            float m = fmaxf(lg[rt][0][r], lg[rt][1][r]);
            #pragma unroll
            for (int off = 8; off >= 1; off >>= 1) m = fmaxf(m, __shfl_xor(m, off));
            if (ln == 0) pmax[rt * 16 + quad * 4 + r][w] = m;
        }
    __syncthreads();
    if (tid < 32) {
        const int grow = row0 + tid;
        rowmax[tid] = fmaxf(fmaxf(pmax[tid][0], pmax[tid][1]), fmaxf(pmax[tid][2], pmax[tid][3]));
        float tu = true_u[(size_t)(grow >> 9) * Vc + pp[grow & 511]];
        int t = (int)floorf(tu * 128.0f);
        tcol[tid] = t < 0 ? 0 : (t > 127 ? 127 : t);
    }
    __syncthreads();
    // per-wave sum-exp and target-pick partials
    #pragma unroll
    for (int rt = 0; rt < 2; ++rt)
        #pragma unroll
        for (int r = 0; r < 4; ++r) {
            const int row = rt * 16 + quad * 4 + r;
            const float mx = rowmax[row];
            const int t = tcol[row];
            float e = expf(lg[rt][0][r] - mx) + expf(lg[rt][1][r] - mx);
            float xt = ((cb3 + ln) == t ? lg[rt][0][r] : 0.f) +
                       ((cb3 + 16 + ln) == t ? lg[rt][1][r] : 0.f);
            #pragma unroll
            for (int off = 8; off >= 1; off >>= 1) {
                e += __shfl_xor(e, off);
                xt += __shfl_xor(xt, off);
            }
            if (ln == 0) { psum[row][w] = e; pxt[row][w] = xt; }
        }
    __syncthreads();
    // final: rows handled by lanes 0..31 of wave 0, reduce, one atomic
    float contrib = 0.f;
    if (tid < 32) {
        const float sum = psum[tid][0] + psum[tid][1] + psum[tid][2] + psum[tid][3];
        const float xt  = pxt[tid][0] + pxt[tid][1] + pxt[tid][2] + pxt[tid][3];
        const float lp = logf(128.0f) + (xt - rowmax[tid]) - logf(sum);
        contrib = -lp;
    }
    if (w == 0) {
        #pragma unroll
        for (int off = 32; off >= 1; off >>= 1) contrib += __shfl_xor(contrib, off);
        if (lane == 0) atomicAdd(&outp[b], contrib);
    }
}

// ---------------------------------------------------------------------------
extern "C" void kernel_launch(void* const* d_in, const int* in_sizes, int n_in,
                              void* d_out, int out_size, void* d_ws, size_t ws_size,
                              hipStream_t stream)
{
    (void)in_sizes; (void)n_in; (void)out_size; (void)ws_size;

    const float* encoded        = (const float*)d_in[0];
    const float* true_u         = (const float*)d_in[1];
    const float* attn_mask      = (const float*)d_in[2];
    const int*   pred_points    = (const int*)d_in[3];
    const int*   neighbor_index = (const int*)d_in[4];
    const float* kW1 = (const float*)d_in[5];
    const float* kb1 = (const float*)d_in[6];
    const float* kW2 = (const float*)d_in[7];
    const float* kb2 = (const float*)d_in[8];
    const float* kW3 = (const float*)d_in[9];
    const float* kb3 = (const float*)d_in[10];
    const float* vW1 = (const float*)d_in[11];
    const float* vb1 = (const float*)d_in[12];
    const float* vW2 = (const float*)d_in[13];
    const float* vb2 = (const float*)d_in[14];
    const float* vW3 = (const float*)d_in[15];
    const float* vb3 = (const float*)d_in[16];
    const float* ds_W  = (const float*)d_in[17];
    const float* ds_b  = (const float*)d_in[18];
    const float* ln1_g = (const float*)d_in[19];
    const float* ln1_b = (const float*)d_in[20];
    const float* ff_W1 = (const float*)d_in[21];
    const float* ff_b1 = (const float*)d_in[22];
    const float* ff_W2 = (const float*)d_in[23];
    const float* ff_b2 = (const float*)d_in[24];
    const float* ln2_g = (const float*)d_in[25];
    const float* ln2_b = (const float*)d_in[26];
    const float* de_W1 = (const float*)d_in[27];
    const float* de_b1 = (const float*)d_in[28];
    const float* de_W2 = (const float*)d_in[29];
    const float* de_b2 = (const float*)d_in[30];
    const float* de_W3 = (const float*)d_in[31];
    const float* de_b3 = (const float*)d_in[32];

    float* out = (float*)d_out;

    // workspace layout
    constexpr size_t KV_ELEMS = (size_t)Lc * Bc * Hc * Vc * 32;  // 8,388,608
    unsigned short* keys = (unsigned short*)d_ws;            // bf16 [l][b][v][256]
    unsigned short* vals = keys + KV_ELEMS;
    float* AV = (float*)(vals + KV_ELEMS);                   // 4096 x 256 f32
    unsigned short* Xbf  = (unsigned short*)(AV + (size_t)ROWS_AT * 256);
    unsigned short* W1t  = Xbf + (size_t)ROWS_KV * 256;      // 32 nets x [256][256]
    unsigned short* W2t  = W1t + (size_t)32 * 65536;
    unsigned short* W3t  = W2t + (size_t)32 * 65536;         // 32 nets x [32][256]
    unsigned short* Wm   = W3t + (size_t)32 * 8192;          // 8 slots x 65536
    unsigned short* AVbf = Wm + (size_t)8 * 65536;           // 4096 x 256 bf16

    (void)hipMemsetAsync(out, 0, Bc * sizeof(float), stream);

    // prep (2 launches)
    conv_x_kernel<<<dim3(ROWS_KV * 256 / 4 / 256), 256, 0, stream>>>(encoded, Xbf);
    transpose_all_kernel<<<dim3(8, 8, 104), 256, 0, stream>>>(
        kW1, vW1, kW2, vW2, kW3, vW3,
        ds_W, ff_W1, ff_W2, de_W1, de_W2, de_W3,
        W1t, W2t, W3t, Wm);
    // misc slots: 0=ds 1=ffW1_0 2=ffW1_1 3=ffW2_0 4=ffW2_1 5=deW1 6=deW2 7=deW3

    // KV MLPs v7c: 16 rg x 16 (l,h) x {k,v}
    kv_mfma_kernel<<<dim3(16, 16, 2), 512, 0, stream>>>(
        Xbf, true_u, W1t, W2t, W3t, kW1, vW1,
        kb1, kb2, kb3, vb1, vb2, vb3, keys, vals);

    // att_value = encoded[:,pred_points,:] @ ds_W + ds_b
    ds_gemm_kernel<<<dim3(ROWS_AT / 32), 256, 0, stream>>>(
        Xbf, Wm + (size_t)0 * 65536, ds_b, AV, pred_points);

    for (int l = 0; l < Lc; ++l) {
        attn_ln_kernel<<<dim3(ROWS_AT), 512, 0, stream>>>(
            keys, vals, neighbor_index, attn_mask,
            ln1_g + l * 256, ln1_b + l * 256, AV, AVbf, l);
        ff_fused_kernel<<<dim3(ROWS_AT / 32), 256, 0, stream>>>(
            AVbf, AV,
            Wm + (size_t)(1 + l) * 65536, ff_b1 + l * 256,
            Wm + (size_t)(3 + l) * 65536, ff_b2 + l * 256,
            ln2_g + l * 256, ln2_b + l * 256, AV, AVbf);
    }

    de_loss_kernel<<<dim3(ROWS_AT / 32), 256, 0, stream>>>(
        AVbf,
        Wm + (size_t)5 * 65536, de_b1,
        Wm + (size_t)6 * 65536, de_b2,
        Wm + (size_t)7 * 65536, de_b3,
        true_u, pred_points, out);
}

// Round 14
// 481.309 us; speedup vs baseline: 1.0986x; 1.0986x over previous
//
#include <hip/hip_runtime.h>
#include <hip/hip_bf16.h>
#include <cstdint>
#include <cstddef>

// Problem dims (compile-time)
constexpr int Bc = 8;
constexpr int Vc = 2048;   // S*T
constexpr int Pc = 512;
constexpr int Hc = 8;
constexpr int Lc = 2;
constexpr int ROWS_KV = Bc * Vc;   // 16384
constexpr int ROWS_AT = Bc * Pc;   // 4096

typedef __attribute__((ext_vector_type(8))) short bf16x8;   // 8 bf16 (4 VGPRs)
typedef __attribute__((ext_vector_type(4))) float f32x4;

static __device__ __forceinline__ unsigned short f2bf(float v) {
    __hip_bfloat16 h = __float2bfloat16(v);
    return *(unsigned short*)&h;
}
static __device__ __forceinline__ float bf2f(unsigned short u) {
    unsigned int x = ((unsigned int)u) << 16;
    return __uint_as_float(x);
}
static __device__ __forceinline__ float bflo(unsigned int u) {
    return __uint_as_float(u << 16);
}
static __device__ __forceinline__ float bfhi(unsigned int u) {
    return __uint_as_float(u & 0xffff0000u);
}

// ---------------------------------------------------------------------------
// Prep: encoded fp32 -> bf16 (row-major [16384][256])
// ---------------------------------------------------------------------------
__global__ __launch_bounds__(256) void conv_x_kernel(
    const float* __restrict__ x, unsigned short* __restrict__ xb)
{
    const int i = blockIdx.x * 256 + threadIdx.x;   // 1 float4 per thread
    float4 v = ((const float4*)x)[i];
    ushort4 o;
    o.x = f2bf(v.x); o.y = f2bf(v.y); o.z = f2bf(v.z); o.w = f2bf(v.w);
    ((ushort4*)xb)[i] = o;
}

// ---------------------------------------------------------------------------
// Merged prep: all weight transposes [K x C] fp32 -> [C x 256] bf16.
// grid z: 0..31 W1 (per net), 32..63 W2, 64..95 W3 (C=32), 96..103 misc.
// misc slots: 0=ds_W 1=ffW1_0 2=ffW1_1 3=ffW2_0 4=ffW2_1 5=deW1 6=deW2 7=deW3(C=128)
// ---------------------------------------------------------------------------
__global__ __launch_bounds__(256) void transpose_all_kernel(
    const float* kW1, const float* vW1, const float* kW2, const float* vW2,
    const float* kW3, const float* vW3,
    const float* ds_W, const float* ff_W1, const float* ff_W2,
    const float* de_W1, const float* de_W2, const float* de_W3,
    unsigned short* __restrict__ W1t, unsigned short* __restrict__ W2t,
    unsigned short* __restrict__ W3t, unsigned short* __restrict__ Wm)
{
    const int z = blockIdx.z;
    const float* src;
    unsigned short* dst;
    int C;
    if (z < 32) {
        const int net = z;
        src = ((net >> 4) ? vW1 : kW1) + (size_t)(net & 15) * 257 * 256;
        dst = W1t + (size_t)net * 65536;
        C = 256;
    } else if (z < 64) {
        const int net = z - 32;
        src = ((net >> 4) ? vW2 : kW2) + (size_t)(net & 15) * 256 * 256;
        dst = W2t + (size_t)net * 65536;
        C = 256;
    } else if (z < 96) {
        const int net = z - 64;
        src = ((net >> 4) ? vW3 : kW3) + (size_t)(net & 15) * 256 * 32;
        dst = W3t + (size_t)net * 8192;
        C = 32;
    } else {
        const int id = z - 96;
        const float* srcs[8] = {ds_W, ff_W1, ff_W1 + (size_t)65536,
                                ff_W2, ff_W2 + (size_t)65536, de_W1, de_W2, de_W3};
        src = srcs[id];
        dst = Wm + (size_t)id * 65536;
        C = (id == 7) ? 128 : 256;
    }
    if (blockIdx.x * 32 >= C) return;
    __shared__ float t[32][33];
    const int c0 = blockIdx.x * 32, k0 = blockIdx.y * 32;
    const int tx = threadIdx.x & 31, ty = threadIdx.x >> 5;
    #pragma unroll
    for (int i = 0; i < 32; i += 8)
        t[ty + i][tx] = src[(size_t)(k0 + ty + i) * C + (c0 + tx)];
    __syncthreads();
    #pragma unroll
    for (int i = 0; i < 32; i += 8)
        dst[(size_t)(c0 + ty + i) * 256 + (k0 + tx)] = f2bf(t[tx][ty + i]);
}

// h-buf XOR swizzle: rows x 256 shorts (32 chunks of 8 shorts).
// chunk c of row r stored at p = c ^ (r & 31).
static __device__ __forceinline__ int hsw_chunk(int row, int ks, int quad) {
    int c = ks * 4 + quad;
    int p = c ^ (row & 31);
    return row * 256 + p * 8;
}
static __device__ __forceinline__ int hsw_elem(int row, int col) {
    int p = (col >> 3) ^ (row & 31);
    return row * 256 + p * 8 + (col & 7);
}

// ---------------------------------------------------------------------------
// Fused 3-layer KV MLP — v7b (R12 config, best measured): weight-resident
// W1/W2 in registers, W3 in 16KB swizzled LDS, 8 waves, 512 blocks.
// Output bf16 [l][b][v][h*32].
// ---------------------------------------------------------------------------
__global__ __launch_bounds__(512, 2) void kv_mfma_kernel(
    const unsigned short* __restrict__ Xbf, const float* __restrict__ true_u,
    const unsigned short* __restrict__ W1t, const unsigned short* __restrict__ W2t,
    const unsigned short* __restrict__ W3t,
    const float* __restrict__ kW1, const float* __restrict__ vW1,
    const float* __restrict__ kb1, const float* __restrict__ kb2, const float* __restrict__ kb3,
    const float* __restrict__ vb1, const float* __restrict__ vb2, const float* __restrict__ vb3,
    unsigned short* __restrict__ keys, unsigned short* __restrict__ vals)
{
    __shared__ unsigned short hbuf[64 * 256];    // 32 KB: X -> h1 -> h2 (swizzled)
    __shared__ unsigned short w3buf[32 * 256];   // 16 KB: W3 slice (swizzled)
    __shared__ float tub[64];                    // true_u tile

    const int tid = threadIdx.x;
    const int w = tid >> 6, lane = tid & 63;
    const int ln = lane & 15, quad = lane >> 4;
    const int lh = blockIdx.y, isv = blockIdx.z;
    const int net = isv * 16 + lh;
    const float* W1f = (isv ? vW1 : kW1) + (size_t)lh * 257 * 256;
    const float* b1  = (isv ? vb1 : kb1) + lh * 256;
    const float* b2  = (isv ? vb2 : kb2) + lh * 256;
    const float* b3  = (isv ? vb3 : kb3) + lh * 32;
    const unsigned short* w1 = W1t + (size_t)net * 65536;
    const unsigned short* w2 = W2t + (size_t)net * 65536;
    const unsigned short* w3 = W3t + (size_t)net * 8192;
    unsigned short* outp = isv ? vals : keys;
    const int base = blockIdx.x * 1024;          // row-group (16 tiles)
    const int cb = w * 32;                       // wave's column base (stages 1-2)

    // ---- one-time: W1/W2 column slices -> registers (32 x 16B loads each) ----
    bf16x8 B1[16], B2[16];
    {
        const unsigned short* p1 = w1 + (size_t)(cb + ln) * 256 + quad * 8;
        const unsigned short* p2 = w2 + (size_t)(cb + ln) * 256 + quad * 8;
        #pragma unroll
        for (int ks = 0; ks < 8; ++ks)
            #pragma unroll
            for (int ct = 0; ct < 2; ++ct) {
                B1[ks * 2 + ct] = *(const bf16x8*)(p1 + (size_t)ct * 16 * 256 + ks * 32);
                B2[ks * 2 + ct] = *(const bf16x8*)(p2 + (size_t)ct * 16 * 256 + ks * 32);
            }
    }
    // ---- one-time: W3 -> swizzled LDS (1024 chunks / 512 threads) ----
    {
        #pragma unroll
        for (int j = 0; j < 2; ++j) {
            const int cidx = tid * 2 + j;
            const int col = cidx >> 5, c = cidx & 31;
            uint4 d = *(const uint4*)(w3 + cidx * 8);
            *(uint4*)&w3buf[col * 256 + (c ^ (col & 31)) * 8] = d;
        }
    }
    // ---- one-time: per-lane epilogue constants ----
    float w1f[2], b1v[2], b2v[2];
    #pragma unroll
    for (int ct = 0; ct < 2; ++ct) {
        const int col = cb + ct * 16 + ln;
        w1f[ct] = W1f[256 * 256 + col];
        b1v[ct] = b1[col];
        b2v[ct] = b2[col];
    }
    const int rt3 = w & 3, ct3 = w >> 2;         // stage-3 tile of this wave
    const float b3v = b3[ct3 * 16 + ln];

    const int b_ = base >> 11;
    const int l_ = lh >> 3, h_ = lh & 7;
    // layout: [l][b][v][h*32 + col]
    unsigned short* ob = outp + (((size_t)l_ * Bc + b_) * Vc) * 256 + h_ * 32;

    const f32x4 zero = {0.f, 0.f, 0.f, 0.f};
    const int xr = tid >> 3, cg = tid & 7;       // X staging: 8 threads/row

    for (int t = 0; t < 16; ++t) {
        const int row0 = base + t * 64;
        __syncthreads();   // prior tile's stage-3 reads complete before X overwrite

        // ---- stage X tile + true_u into LDS ----
        {
            const unsigned short* gx = Xbf + (size_t)(row0 + xr) * 256;
            #pragma unroll
            for (int j = 0; j < 4; ++j) {
                const int c = j * 8 + cg;
                uint4 d = *(const uint4*)(gx + c * 8);
                *(uint4*)&hbuf[xr * 256 + (c ^ (xr & 31)) * 8] = d;
            }
            if (tid < 64) tub[tid] = true_u[row0 + tid];
        }
        __syncthreads();

        // ---- stage 1: h1 = relu(X @ W1 + tu*W1row256 + b1) ----
        f32x4 acc[4][2];
        #pragma unroll
        for (int rt = 0; rt < 4; ++rt)
            #pragma unroll
            for (int ct = 0; ct < 2; ++ct) acc[rt][ct] = zero;
        #pragma unroll
        for (int ks = 0; ks < 8; ++ks) {
            bf16x8 A[4];
            #pragma unroll
            for (int rt = 0; rt < 4; ++rt)
                A[rt] = *(const bf16x8*)&hbuf[hsw_chunk(rt * 16 + ln, ks, quad)];
            #pragma unroll
            for (int rt = 0; rt < 4; ++rt)
                #pragma unroll
                for (int ct = 0; ct < 2; ++ct)
                    acc[rt][ct] = __builtin_amdgcn_mfma_f32_16x16x32_bf16(A[rt], B1[ks * 2 + ct], acc[rt][ct], 0, 0, 0);
        }
        __syncthreads();   // all X reads done before h1 overwrite
        #pragma unroll
        for (int ct = 0; ct < 2; ++ct) {
            const int col = cb + ct * 16 + ln;
            #pragma unroll
            for (int rt = 0; rt < 4; ++rt)
                #pragma unroll
                for (int r = 0; r < 4; ++r) {
                    const int row = rt * 16 + quad * 4 + r;
                    float v = fmaxf(acc[rt][ct][r] + b1v[ct] + tub[row] * w1f[ct], 0.f);
                    hbuf[hsw_elem(row, col)] = f2bf(v);
                }
        }
        __syncthreads();

        // ---- stage 2: h2 = relu(h1 @ W2 + b2) ----
        #pragma unroll
        for (int rt = 0; rt < 4; ++rt)
            #pragma unroll
            for (int ct = 0; ct < 2; ++ct) acc[rt][ct] = zero;
        #pragma unroll
        for (int ks = 0; ks < 8; ++ks) {
            bf16x8 A[4];
            #pragma unroll
            for (int rt = 0; rt < 4; ++rt)
                A[rt] = *(const bf16x8*)&hbuf[hsw_chunk(rt * 16 + ln, ks, quad)];
            #pragma unroll
            for (int rt = 0; rt < 4; ++rt)
                #pragma unroll
                for (int ct = 0; ct < 2; ++ct)
                    acc[rt][ct] = __builtin_amdgcn_mfma_f32_16x16x32_bf16(A[rt], B2[ks * 2 + ct], acc[rt][ct], 0, 0, 0);
        }
        __syncthreads();   // all h1 reads done before h2 overwrite
        #pragma unroll
        for (int ct = 0; ct < 2; ++ct) {
            const int col = cb + ct * 16 + ln;
            #pragma unroll
            for (int rt = 0; rt < 4; ++rt)
                #pragma unroll
                for (int r = 0; r < 4; ++r) {
                    const int row = rt * 16 + quad * 4 + r;
                    hbuf[hsw_elem(row, col)] = f2bf(fmaxf(acc[rt][ct][r] + b2v[ct], 0.f));
                }
        }
        __syncthreads();

        // ---- stage 3: out = h2 @ W3 + b3; wave w -> 16x16 tile (rt3, ct3) ----
        f32x4 acc3 = zero;
        #pragma unroll
        for (int ks = 0; ks < 8; ++ks) {
            bf16x8 A  = *(const bf16x8*)&hbuf[hsw_chunk(rt3 * 16 + ln, ks, quad)];
            bf16x8 Bv = *(const bf16x8*)&w3buf[hsw_chunk(ct3 * 16 + ln, ks, quad)];
            acc3 = __builtin_amdgcn_mfma_f32_16x16x32_bf16(A, Bv, acc3, 0, 0, 0);
        }
        #pragma unroll
        for (int r = 0; r < 4; ++r) {
            const int grow = row0 + rt3 * 16 + quad * 4 + r;
            ob[(size_t)(grow & 2047) * 256 + ct3 * 16 + ln] = f2bf(acc3[r] + b3v);
        }
    }
}

// ---------------------------------------------------------------------------
// ds GEMM: AV[4096 x 256] = Xbf[gathered rows] @ ds_Wt^T + ds_b  (fp32 out)
// ---------------------------------------------------------------------------
__global__ __launch_bounds__(256) void ds_gemm_kernel(
    const unsigned short* __restrict__ Abf, const unsigned short* __restrict__ Wt,
    const float* __restrict__ bias, float* __restrict__ outF,
    const int* __restrict__ pp)
{
    const int tid = threadIdx.x;
    const int w = tid >> 6, lane = tid & 63;
    const int ln = lane & 15, quad = lane >> 4;
    const int row0 = blockIdx.x * 32;
    const int cb = w * 64;

    const f32x4 zero = {0.f, 0.f, 0.f, 0.f};
    f32x4 acc[2][4];
    #pragma unroll
    for (int rt = 0; rt < 2; ++rt)
        #pragma unroll
        for (int ct = 0; ct < 4; ++ct) acc[rt][ct] = zero;

    size_t arow[2];
    #pragma unroll
    for (int rt = 0; rt < 2; ++rt) {
        int ra = row0 + rt * 16 + ln;
        arow[rt] = (size_t)(ra >> 9) * Vc + pp[ra & 511];
    }
    const unsigned short* wb = Wt + (size_t)(cb + ln) * 256 + quad * 8;
    #pragma unroll
    for (int ks = 0; ks < 8; ++ks) {
        bf16x8 A[2], Bv[4];
        #pragma unroll
        for (int rt = 0; rt < 2; ++rt)
            A[rt] = *(const bf16x8*)(Abf + arow[rt] * 256 + ks * 32 + quad * 8);
        #pragma unroll
        for (int ct = 0; ct < 4; ++ct)
            Bv[ct] = *(const bf16x8*)(wb + (size_t)ct * 16 * 256 + ks * 32);
        #pragma unroll
        for (int rt = 0; rt < 2; ++rt)
            #pragma unroll
            for (int ct = 0; ct < 4; ++ct)
                acc[rt][ct] = __builtin_amdgcn_mfma_f32_16x16x32_bf16(A[rt], Bv[ct], acc[rt][ct], 0, 0, 0);
    }
    #pragma unroll
    for (int ct = 0; ct < 4; ++ct) {
        const int col = cb + ct * 16 + ln;
        const float bb = bias[col];
        #pragma unroll
        for (int rt = 0; rt < 2; ++rt)
            #pragma unroll
            for (int r = 0; r < 4; ++r)
                outF[(size_t)(row0 + rt * 16 + quad * 4 + r) * 256 + col] = acc[rt][ct][r] + bb;
    }
}

// ---------------------------------------------------------------------------
// Fused attention + residual + LayerNorm1 for one layer.
// PV phase vectorized: lane = (nb4 = n>>2, cg8 = (n&3)*8); per pass one
// dwordx4 covers 8 cols of one neighbor; butterfly over nb4 groups.
// ---------------------------------------------------------------------------
__global__ __launch_bounds__(512) void attn_ln_kernel(
    const unsigned short* __restrict__ keys, const unsigned short* __restrict__ vals,
    const int* __restrict__ nbr, const float* __restrict__ mask,
    const float* __restrict__ g, const float* __restrict__ be,
    float* __restrict__ AV, unsigned short* __restrict__ AVbf, const int l)
{
    __shared__ float qs[256];
    __shared__ float wts[8 * 64];
    __shared__ float att_s[256];
    __shared__ int ni[64];
    __shared__ float red[4], red2[4];

    const int bid = blockIdx.x;
    const int row = ((bid & 7) << 9) | (bid >> 3);   // b = bid&7, p = bid>>3
    const int b = row >> 9, p = row & 511;
    const int tid = threadIdx.x;
    const int h = tid >> 6, n = tid & 63;

    if (tid < 256) qs[tid] = AV[(size_t)row * 256 + tid];
    if (tid < 64)  ni[tid] = nbr[p * 64 + tid];
    __syncthreads();

    const unsigned short* kvbase = keys + (((size_t)l * Bc + b) * Vc) * 256;
    const unsigned short* vvbase = vals + (((size_t)l * Bc + b) * Vc) * 256;

    // phase 1: scores + softmax (per head-wave)
    {
        const int vi = ni[n];
        const unsigned short* kp = kvbase + (size_t)vi * 256 + h * 32;
        const float* qh = qs + h * 32;
        float s = 0.f;
        #pragma unroll
        for (int j = 0; j < 4; ++j) {
            uint4 u = *(const uint4*)(kp + j * 8);
            const float* q = qh + j * 8;
            s += q[0] * bflo(u.x) + q[1] * bfhi(u.x);
            s += q[2] * bflo(u.y) + q[3] * bfhi(u.y);
            s += q[4] * bflo(u.z) + q[5] * bfhi(u.z);
            s += q[6] * bflo(u.w) + q[7] * bfhi(u.w);
        }
        s = (s - mask[p * 64 + n]) * 0.17677669529663689f;  // AD^-0.5
        float mx = s;
        #pragma unroll
        for (int off = 32; off >= 1; off >>= 1) mx = fmaxf(mx, __shfl_xor(mx, off));
        float e = expf(s - mx);
        float sum = e;
        #pragma unroll
        for (int off = 32; off >= 1; off >>= 1) sum += __shfl_xor(sum, off);
        wts[h * 64 + n] = e / sum;   // same-wave producer/consumer, no barrier
    }

    // phase 2: PV vectorized. lane: nb4 = n>>2 (nbr group), cg8 = (n&3)*8.
    {
        const int nb4 = n >> 2, cg8 = (n & 3) * 8;
        float a[8];
        #pragma unroll
        for (int j = 0; j < 8; ++j) a[j] = 0.f;
        #pragma unroll
        for (int pass = 0; pass < 4; ++pass) {
            const int nn = pass * 16 + nb4;
            const float wgt = wts[h * 64 + nn];
            const unsigned short* vp = vvbase + (size_t)ni[nn] * 256 + h * 32 + cg8;
            uint4 u = *(const uint4*)vp;
            a[0] += wgt * bflo(u.x); a[1] += wgt * bfhi(u.x);
            a[2] += wgt * bflo(u.y); a[3] += wgt * bfhi(u.y);
            a[4] += wgt * bflo(u.z); a[5] += wgt * bfhi(u.z);
            a[6] += wgt * bflo(u.w); a[7] += wgt * bfhi(u.w);
        }
        // butterfly over nb4 (lane bits 2..5)
        #pragma unroll
        for (int off = 4; off <= 32; off <<= 1)
            #pragma unroll
            for (int j = 0; j < 8; ++j)
                a[j] += __shfl_xor(a[j], off);
        if (nb4 == 0)
            #pragma unroll
            for (int j = 0; j < 8; ++j)
                att_s[h * 32 + cg8 + j] = a[j];
    }
    __syncthreads();

    // phase 3: LN(AV + att) over 256 (first 4 waves carry data)
    float x = 0.f;
    if (tid < 256) x = qs[tid] + att_s[tid];
    float s = x;
    #pragma unroll
    for (int off = 32; off >= 1; off >>= 1) s += __shfl_xor(s, off);
    if ((tid & 63) == 0 && tid < 256) red[tid >> 6] = s;
    __syncthreads();
    const float mu = (red[0] + red[1] + red[2] + red[3]) * (1.0f / 256.0f);
    const float dx = x - mu;
    float v = dx * dx;
    #pragma unroll
    for (int off = 32; off >= 1; off >>= 1) v += __shfl_xor(v, off);
    if ((tid & 63) == 0 && tid < 256) red2[tid >> 6] = v;
    __syncthreads();
    if (tid < 256) {
        const float var = (red2[0] + red2[1] + red2[2] + red2[3]) * (1.0f / 256.0f);
        float o = dx * (1.0f / sqrtf(var + 1e-5f)) * g[tid] + be[tid];
        AV[(size_t)row * 256 + tid] = o;
        AVbf[(size_t)row * 256 + tid] = f2bf(o);
    }
}

// ---------------------------------------------------------------------------
// Fused FF block: AV = LN2(AV + relu(AVbf@W1+b1)@W2 + b2)  -> AV fp32 + AVbf.
// ---------------------------------------------------------------------------
__global__ __launch_bounds__(256) void ff_fused_kernel(
    const unsigned short* __restrict__ Abf, const float* __restrict__ resF,
    const unsigned short* __restrict__ W1t, const float* __restrict__ b1,
    const unsigned short* __restrict__ W2t, const float* __restrict__ b2,
    const float* __restrict__ g, const float* __restrict__ be,
    float* __restrict__ outF, unsigned short* __restrict__ outB)
{
    __shared__ unsigned short hbuf[32 * 256];   // 16 KB
    __shared__ float psum[32][4], psq[32][4];

    const int tid = threadIdx.x;
    const int w = tid >> 6, lane = tid & 63;
    const int ln = lane & 15, quad = lane >> 4;
    const int row0 = blockIdx.x * 32;
    const int cb = w * 64;

    const f32x4 zero = {0.f, 0.f, 0.f, 0.f};
    f32x4 acc[2][4];

    // ---- stage A: T1 = relu(A@W1 + b1) -> hbuf ----
    #pragma unroll
    for (int rt = 0; rt < 2; ++rt)
        #pragma unroll
        for (int ct = 0; ct < 4; ++ct) acc[rt][ct] = zero;
    {
        const unsigned short* ab = Abf + ((size_t)row0 + ln) * 256 + quad * 8;
        const unsigned short* wb = W1t + (size_t)(cb + ln) * 256 + quad * 8;
        #pragma unroll
        for (int ks = 0; ks < 8; ++ks) {
            bf16x8 A[2], Bv[4];
            #pragma unroll
            for (int rt = 0; rt < 2; ++rt)
                A[rt] = *(const bf16x8*)(ab + (size_t)rt * 16 * 256 + ks * 32);
            #pragma unroll
            for (int ct = 0; ct < 4; ++ct)
                Bv[ct] = *(const bf16x8*)(wb + (size_t)ct * 16 * 256 + ks * 32);
            #pragma unroll
            for (int rt = 0; rt < 2; ++rt)
                #pragma unroll
                for (int ct = 0; ct < 4; ++ct)
                    acc[rt][ct] = __builtin_amdgcn_mfma_f32_16x16x32_bf16(A[rt], Bv[ct], acc[rt][ct], 0, 0, 0);
        }
    }
    #pragma unroll
    for (int ct = 0; ct < 4; ++ct) {
        const int col = cb + ct * 16 + ln;
        const float bb = b1[col];
        #pragma unroll
        for (int rt = 0; rt < 2; ++rt)
            #pragma unroll
            for (int r = 0; r < 4; ++r) {
                const int row = rt * 16 + quad * 4 + r;
                hbuf[hsw_elem(row, col)] = f2bf(fmaxf(acc[rt][ct][r] + bb, 0.f));
            }
    }
    __syncthreads();

    // ---- stage B: T2 = T1@W2 + b2 (+ residual) ----
    #pragma unroll
    for (int rt = 0; rt < 2; ++rt)
        #pragma unroll
        for (int ct = 0; ct < 4; ++ct) acc[rt][ct] = zero;
    {
        const unsigned short* wb = W2t + (size_t)(cb + ln) * 256 + quad * 8;
        #pragma unroll
        for (int ks = 0; ks < 8; ++ks) {
            bf16x8 A[2], Bv[4];
            #pragma unroll
            for (int rt = 0; rt < 2; ++rt)
                A[rt] = *(const bf16x8*)&hbuf[hsw_chunk(rt * 16 + ln, ks, quad)];
            #pragma unroll
            for (int ct = 0; ct < 4; ++ct)
                Bv[ct] = *(const bf16x8*)(wb + (size_t)ct * 16 * 256 + ks * 32);
            #pragma unroll
            for (int rt = 0; rt < 2; ++rt)
                #pragma unroll
                for (int ct = 0; ct < 4; ++ct)
                    acc[rt][ct] = __builtin_amdgcn_mfma_f32_16x16x32_bf16(A[rt], Bv[ct], acc[rt][ct], 0, 0, 0);
        }
    }
    // v = T2 + b2 + residual; per-wave partial sums for LN
    float vv[2][4][4];
    #pragma unroll
    for (int ct = 0; ct < 4; ++ct) {
        const int col = cb + ct * 16 + ln;
        const float bb = b2[col];
        #pragma unroll
        for (int rt = 0; rt < 2; ++rt)
            #pragma unroll
            for (int r = 0; r < 4; ++r) {
                const int row = rt * 16 + quad * 4 + r;
                float res = resF[(size_t)(row0 + row) * 256 + col];
                vv[rt][ct][r] = acc[rt][ct][r] + bb + res;
            }
    }
    #pragma unroll
    for (int rt = 0; rt < 2; ++rt)
        #pragma unroll
        for (int r = 0; r < 4; ++r) {
            float sl = 0.f, ql = 0.f;
            #pragma unroll
            for (int ct = 0; ct < 4; ++ct) { float t = vv[rt][ct][r]; sl += t; ql += t * t; }
            #pragma unroll
            for (int off = 8; off >= 1; off >>= 1) {
                sl += __shfl_xor(sl, off);
                ql += __shfl_xor(ql, off);
            }
            if (ln == 0) {
                const int row = rt * 16 + quad * 4 + r;
                psum[row][w] = sl; psq[row][w] = ql;
            }
        }
    __syncthreads();

    // ---- LN epilogue ----
    #pragma unroll
    for (int rt = 0; rt < 2; ++rt)
        #pragma unroll
        for (int r = 0; r < 4; ++r) {
            const int row = rt * 16 + quad * 4 + r;
            const float mu = (psum[row][0] + psum[row][1] + psum[row][2] + psum[row][3]) * (1.0f / 256.0f);
            const float eq = (psq[row][0] + psq[row][1] + psq[row][2] + psq[row][3]) * (1.0f / 256.0f);
            const float rstd = 1.0f / sqrtf(fmaxf(eq - mu * mu, 0.f) + 1e-5f);
            #pragma unroll
            for (int ct = 0; ct < 4; ++ct) {
                const int col = cb + ct * 16 + ln;
                float o = (vv[rt][ct][r] - mu) * rstd * g[col] + be[col];
                outF[(size_t)(row0 + row) * 256 + col] = o;
                outB[(size_t)(row0 + row) * 256 + col] = f2bf(o);
            }
        }
}

// ---------------------------------------------------------------------------
// Fused decoder + loss
// ---------------------------------------------------------------------------
__global__ __launch_bounds__(256) void de_loss_kernel(
    const unsigned short* __restrict__ Abf,
    const unsigned short* __restrict__ W1t, const float* __restrict__ b1,
    const unsigned short* __restrict__ W2t, const float* __restrict__ b2,
    const unsigned short* __restrict__ W3t, const float* __restrict__ b3,
    const float* __restrict__ true_u, const int* __restrict__ pp,
    float* __restrict__ outp)
{
    __shared__ unsigned short hbuf[32 * 256];   // 16 KB
    __shared__ float pmax[32][4], psum[32][4], pxt[32][4];
    __shared__ float rowmax[32];
    __shared__ int tcol[32];

    const int tid = threadIdx.x;
    const int w = tid >> 6, lane = tid & 63;
    const int ln = lane & 15, quad = lane >> 4;
    const int row0 = blockIdx.x * 32;
    const int b = row0 >> 9;

    const f32x4 zero = {0.f, 0.f, 0.f, 0.f};
    f32x4 acc[2][4];

    // ---- stage 1: h1 ----
    #pragma unroll
    for (int rt = 0; rt < 2; ++rt)
        #pragma unroll
        for (int ct = 0; ct < 4; ++ct) acc[rt][ct] = zero;
    {
        const unsigned short* ab = Abf + ((size_t)row0 + ln) * 256 + quad * 8;
        const unsigned short* wb = W1t + (size_t)(w * 64 + ln) * 256 + quad * 8;
        #pragma unroll
        for (int ks = 0; ks < 8; ++ks) {
            bf16x8 A[2], Bv[4];
            #pragma unroll
            for (int rt = 0; rt < 2; ++rt)
                A[rt] = *(const bf16x8*)(ab + (size_t)rt * 16 * 256 + ks * 32);
            #pragma unroll
            for (int ct = 0; ct < 4; ++ct)
                Bv[ct] = *(const bf16x8*)(wb + (size_t)ct * 16 * 256 + ks * 32);
            #pragma unroll
            for (int rt = 0; rt < 2; ++rt)
                #pragma unroll
                for (int ct = 0; ct < 4; ++ct)
                    acc[rt][ct] = __builtin_amdgcn_mfma_f32_16x16x32_bf16(A[rt], Bv[ct], acc[rt][ct], 0, 0, 0);
        }
    }
    #pragma unroll
    for (int ct = 0; ct < 4; ++ct) {
        const int col = w * 64 + ct * 16 + ln;
        const float bb = b1[col];
        #pragma unroll
        for (int rt = 0; rt < 2; ++rt)
            #pragma unroll
            for (int r = 0; r < 4; ++r) {
                const int row = rt * 16 + quad * 4 + r;
                hbuf[hsw_elem(row, col)] = f2bf(fmaxf(acc[rt][ct][r] + bb, 0.f));
            }
    }
    __syncthreads();

    // ---- stage 2: h2 ----
    #pragma unroll
    for (int rt = 0; rt < 2; ++rt)
        #pragma unroll
        for (int ct = 0; ct < 4; ++ct) acc[rt][ct] = zero;
    {
        const unsigned short* wb = W2t + (size_t)(w * 64 + ln) * 256 + quad * 8;
        #pragma unroll
        for (int ks = 0; ks < 8; ++ks) {
            bf16x8 A[2], Bv[4];
            #pragma unroll
            for (int rt = 0; rt < 2; ++rt)
                A[rt] = *(const bf16x8*)&hbuf[hsw_chunk(rt * 16 + ln, ks, quad)];
            #pragma unroll
            for (int ct = 0; ct < 4; ++ct)
                Bv[ct] = *(const bf16x8*)(wb + (size_t)ct * 16 * 256 + ks * 32);
            #pragma unroll
            for (int rt = 0; rt < 2; ++rt)
                #pragma unroll
                for (int ct = 0; ct < 4; ++ct)
                    acc[rt][ct] = __builtin_amdgcn_mfma_f32_16x16x32_bf16(A[rt], Bv[ct], acc[rt][ct], 0, 0, 0);
        }
    }
    __syncthreads();
    #pragma unroll
    for (int ct = 0; ct < 4; ++ct) {
        const int col = w * 64 + ct * 16 + ln;
        const float bb = b2[col];
        #pragma unroll
        for (int rt = 0; rt < 2; ++rt)
            #pragma unroll
            for (int r = 0; r < 4; ++r) {
                const int row = rt * 16 + quad * 4 + r;
                hbuf[hsw_elem(row, col)] = f2bf(fmaxf(acc[rt][ct][r] + bb, 0.f));
            }
    }
    __syncthreads();

    // ---- stage 3: logits (128 cols; wave w -> cols w*32..+31) ----
    const int cb3 = w * 32;
    f32x4 a3[2][2];
    a3[0][0] = zero; a3[0][1] = zero; a3[1][0] = zero; a3[1][1] = zero;
    #pragma unroll
    for (int ks = 0; ks < 8; ++ks) {
        bf16x8 A[2];
        #pragma unroll
        for (int rt = 0; rt < 2; ++rt)
            A[rt] = *(const bf16x8*)&hbuf[hsw_chunk(rt * 16 + ln, ks, quad)];
        #pragma unroll
        for (int ct = 0; ct < 2; ++ct) {
            bf16x8 Bv = *(const bf16x8*)(W3t + (size_t)(cb3 + ct * 16 + ln) * 256 + ks * 32 + quad * 8);
            #pragma unroll
            for (int rt = 0; rt < 2; ++rt)
                a3[rt][ct] = __builtin_amdgcn_mfma_f32_16x16x32_bf16(A[rt], Bv, a3[rt][ct], 0, 0, 0);
        }
    }
    float lg[2][2][4];
    #pragma unroll
    for (int ct = 0; ct < 2; ++ct) {
        const float bb = b3[cb3 + ct * 16 + ln];
        #pragma unroll
        for (int rt = 0; rt < 2; ++rt)
            #pragma unroll
            for (int r = 0; r < 4; ++r) lg[rt][ct][r] = a3[rt][ct][r] + bb;
    }

    // per-wave row-max partials
    #pragma unroll
    for (int rt = 0; rt < 2; ++rt)
        #pragma unroll
        for (int r = 0; r < 4; ++r) {
            float m = fmaxf(lg[rt][0][r], lg[rt][1][r]);
            #pragma unroll
            for (int off = 8; off >= 1; off >>= 1) m = fmaxf(m, __shfl_xor(m, off));
            if (ln == 0) pmax[rt * 16 + quad * 4 + r][w] = m;
        }
    __syncthreads();
    if (tid < 32) {
        const int grow = row0 + tid;
        rowmax[tid] = fmaxf(fmaxf(pmax[tid][0], pmax[tid][1]), fmaxf(pmax[tid][2], pmax[tid][3]));
        float tu = true_u[(size_t)(grow >> 9) * Vc + pp[grow & 511]];
        int t = (int)floorf(tu * 128.0f);
        tcol[tid] = t < 0 ? 0 : (t > 127 ? 127 : t);
    }
    __syncthreads();
    // per-wave sum-exp and target-pick partials
    #pragma unroll
    for (int rt = 0; rt < 2; ++rt)
        #pragma unroll
        for (int r = 0; r < 4; ++r) {
            const int row = rt * 16 + quad * 4 + r;
            const float mx = rowmax[row];
            const int t = tcol[row];
            float e = expf(lg[rt][0][r] - mx) + expf(lg[rt][1][r] - mx);
            float xt = ((cb3 + ln) == t ? lg[rt][0][r] : 0.f) +
                       ((cb3 + 16 + ln) == t ? lg[rt][1][r] : 0.f);
            #pragma unroll
            for (int off = 8; off >= 1; off >>= 1) {
                e += __shfl_xor(e, off);
                xt += __shfl_xor(xt, off);
            }
            if (ln == 0) { psum[row][w] = e; pxt[row][w] = xt; }
        }
    __syncthreads();
    // final: rows handled by lanes 0..31 of wave 0, reduce, one atomic
    float contrib = 0.f;
    if (tid < 32) {
        const float sum = psum[tid][0] + psum[tid][1] + psum[tid][2] + psum[tid][3];
        const float xt  = pxt[tid][0] + pxt[tid][1] + pxt[tid][2] + pxt[tid][3];
        const float lp = logf(128.0f) + (xt - rowmax[tid]) - logf(sum);
        contrib = -lp;
    }
    if (w == 0) {
        #pragma unroll
        for (int off = 32; off >= 1; off >>= 1) contrib += __shfl_xor(contrib, off);
        if (lane == 0) atomicAdd(&outp[b], contrib);
    }
}

// ---------------------------------------------------------------------------
extern "C" void kernel_launch(void* const* d_in, const int* in_sizes, int n_in,
                              void* d_out, int out_size, void* d_ws, size_t ws_size,
                              hipStream_t stream)
{
    (void)in_sizes; (void)n_in; (void)out_size; (void)ws_size;

    const float* encoded        = (const float*)d_in[0];
    const float* true_u         = (const float*)d_in[1];
    const float* attn_mask      = (const float*)d_in[2];
    const int*   pred_points    = (const int*)d_in[3];
    const int*   neighbor_index = (const int*)d_in[4];
    const float* kW1 = (const float*)d_in[5];
    const float* kb1 = (const float*)d_in[6];
    const float* kW2 = (const float*)d_in[7];
    const float* kb2 = (const float*)d_in[8];
    const float* kW3 = (const float*)d_in[9];
    const float* kb3 = (const float*)d_in[10];
    const float* vW1 = (const float*)d_in[11];
    const float* vb1 = (const float*)d_in[12];
    const float* vW2 = (const float*)d_in[13];
    const float* vb2 = (const float*)d_in[14];
    const float* vW3 = (const float*)d_in[15];
    const float* vb3 = (const float*)d_in[16];
    const float* ds_W  = (const float*)d_in[17];
    const float* ds_b  = (const float*)d_in[18];
    const float* ln1_g = (const float*)d_in[19];
    const float* ln1_b = (const float*)d_in[20];
    const float* ff_W1 = (const float*)d_in[21];
    const float* ff_b1 = (const float*)d_in[22];
    const float* ff_W2 = (const float*)d_in[23];
    const float* ff_b2 = (const float*)d_in[24];
    const float* ln2_g = (const float*)d_in[25];
    const float* ln2_b = (const float*)d_in[26];
    const float* de_W1 = (const float*)d_in[27];
    const float* de_b1 = (const float*)d_in[28];
    const float* de_W2 = (const float*)d_in[29];
    const float* de_b2 = (const float*)d_in[30];
    const float* de_W3 = (const float*)d_in[31];
    const float* de_b3 = (const float*)d_in[32];

    float* out = (float*)d_out;

    // workspace layout
    constexpr size_t KV_ELEMS = (size_t)Lc * Bc * Hc * Vc * 32;  // 8,388,608
    unsigned short* keys = (unsigned short*)d_ws;            // bf16 [l][b][v][256]
    unsigned short* vals = keys + KV_ELEMS;
    float* AV = (float*)(vals + KV_ELEMS);                   // 4096 x 256 f32
    unsigned short* Xbf  = (unsigned short*)(AV + (size_t)ROWS_AT * 256);
    unsigned short* W1t  = Xbf + (size_t)ROWS_KV * 256;      // 32 nets x [256][256]
    unsigned short* W2t  = W1t + (size_t)32 * 65536;
    unsigned short* W3t  = W2t + (size_t)32 * 65536;         // 32 nets x [32][256]
    unsigned short* Wm   = W3t + (size_t)32 * 8192;          // 8 slots x 65536
    unsigned short* AVbf = Wm + (size_t)8 * 65536;           // 4096 x 256 bf16

    (void)hipMemsetAsync(out, 0, Bc * sizeof(float), stream);

    // prep (2 launches)
    conv_x_kernel<<<dim3(ROWS_KV * 256 / 4 / 256), 256, 0, stream>>>(encoded, Xbf);
    transpose_all_kernel<<<dim3(8, 8, 104), 256, 0, stream>>>(
        kW1, vW1, kW2, vW2, kW3, vW3,
        ds_W, ff_W1, ff_W2, de_W1, de_W2, de_W3,
        W1t, W2t, W3t, Wm);
    // misc slots: 0=ds 1=ffW1_0 2=ffW1_1 3=ffW2_0 4=ffW2_1 5=deW1 6=deW2 7=deW3

    // KV MLPs v7b (R12 config): 16 rg x 16 (l,h) x {k,v}
    kv_mfma_kernel<<<dim3(16, 16, 2), 512, 0, stream>>>(
        Xbf, true_u, W1t, W2t, W3t, kW1, vW1,
        kb1, kb2, kb3, vb1, vb2, vb3, keys, vals);

    // att_value = encoded[:,pred_points,:] @ ds_W + ds_b
    ds_gemm_kernel<<<dim3(ROWS_AT / 32), 256, 0, stream>>>(
        Xbf, Wm + (size_t)0 * 65536, ds_b, AV, pred_points);

    for (int l = 0; l < Lc; ++l) {
        attn_ln_kernel<<<dim3(ROWS_AT), 512, 0, stream>>>(
            keys, vals, neighbor_index, attn_mask,
            ln1_g + l * 256, ln1_b + l * 256, AV, AVbf, l);
        ff_fused_kernel<<<dim3(ROWS_AT / 32), 256, 0, stream>>>(
            AVbf, AV,
            Wm + (size_t)(1 + l) * 65536, ff_b1 + l * 256,
            Wm + (size_t)(3 + l) * 65536, ff_b2 + l * 256,
            ln2_g + l * 256, ln2_b + l * 256, AV, AVbf);
    }

    de_loss_kernel<<<dim3(ROWS_AT / 32), 256, 0, stream>>>(
        AVbf,
        Wm + (size_t)5 * 65536, de_b1,
        Wm + (size_t)6 * 65536, de_b2,
        Wm + (size_t)7 * 65536, de_b3,
        true_u, pred_points, out);
}

// Round 15
// 474.684 us; speedup vs baseline: 1.1140x; 1.0140x over previous
//
#include <hip/hip_runtime.h>
#include <hip/hip_bf16.h>
#include <cstdint>
#include <cstddef>

// Problem dims (compile-time)
constexpr int Bc = 8;
constexpr int Vc = 2048;   // S*T
constexpr int Pc = 512;
constexpr int Hc = 8;
constexpr int Lc = 2;
constexpr int ROWS_KV = Bc * Vc;   // 16384
constexpr int ROWS_AT = Bc * Pc;   // 4096

typedef __attribute__((ext_vector_type(8))) short bf16x8;   // 8 bf16 (4 VGPRs)
typedef __attribute__((ext_vector_type(4))) float f32x4;

static __device__ __forceinline__ unsigned short f2bf(float v) {
    __hip_bfloat16 h = __float2bfloat16(v);
    return *(unsigned short*)&h;
}
static __device__ __forceinline__ float bf2f(unsigned short u) {
    unsigned int x = ((unsigned int)u) << 16;
    return __uint_as_float(x);
}
static __device__ __forceinline__ float bflo(unsigned int u) {
    return __uint_as_float(u << 16);
}
static __device__ __forceinline__ float bfhi(unsigned int u) {
    return __uint_as_float(u & 0xffff0000u);
}

// ---------------------------------------------------------------------------
// Prep: encoded fp32 -> bf16 (row-major [16384][256])
// ---------------------------------------------------------------------------
__global__ __launch_bounds__(256) void conv_x_kernel(
    const float* __restrict__ x, unsigned short* __restrict__ xb)
{
    const int i = blockIdx.x * 256 + threadIdx.x;   // 1 float4 per thread
    float4 v = ((const float4*)x)[i];
    ushort4 o;
    o.x = f2bf(v.x); o.y = f2bf(v.y); o.z = f2bf(v.z); o.w = f2bf(v.w);
    ((ushort4*)xb)[i] = o;
}

// ---------------------------------------------------------------------------
// Merged prep: all weight transposes [K x C] fp32 -> [C x 256] bf16.
// ---------------------------------------------------------------------------
__global__ __launch_bounds__(256) void transpose_all_kernel(
    const float* kW1, const float* vW1, const float* kW2, const float* vW2,
    const float* kW3, const float* vW3,
    const float* ds_W, const float* ff_W1, const float* ff_W2,
    const float* de_W1, const float* de_W2, const float* de_W3,
    unsigned short* __restrict__ W1t, unsigned short* __restrict__ W2t,
    unsigned short* __restrict__ W3t, unsigned short* __restrict__ Wm)
{
    const int z = blockIdx.z;
    const float* src;
    unsigned short* dst;
    int C;
    if (z < 32) {
        const int net = z;
        src = ((net >> 4) ? vW1 : kW1) + (size_t)(net & 15) * 257 * 256;
        dst = W1t + (size_t)net * 65536;
        C = 256;
    } else if (z < 64) {
        const int net = z - 32;
        src = ((net >> 4) ? vW2 : kW2) + (size_t)(net & 15) * 256 * 256;
        dst = W2t + (size_t)net * 65536;
        C = 256;
    } else if (z < 96) {
        const int net = z - 64;
        src = ((net >> 4) ? vW3 : kW3) + (size_t)(net & 15) * 256 * 32;
        dst = W3t + (size_t)net * 8192;
        C = 32;
    } else {
        const int id = z - 96;
        const float* srcs[8] = {ds_W, ff_W1, ff_W1 + (size_t)65536,
                                ff_W2, ff_W2 + (size_t)65536, de_W1, de_W2, de_W3};
        src = srcs[id];
        dst = Wm + (size_t)id * 65536;
        C = (id == 7) ? 128 : 256;
    }
    if (blockIdx.x * 32 >= C) return;
    __shared__ float t[32][33];
    const int c0 = blockIdx.x * 32, k0 = blockIdx.y * 32;
    const int tx = threadIdx.x & 31, ty = threadIdx.x >> 5;
    #pragma unroll
    for (int i = 0; i < 32; i += 8)
        t[ty + i][tx] = src[(size_t)(k0 + ty + i) * C + (c0 + tx)];
    __syncthreads();
    #pragma unroll
    for (int i = 0; i < 32; i += 8)
        dst[(size_t)(c0 + ty + i) * 256 + (k0 + tx)] = f2bf(t[tx][ty + i]);
}

// h-buf XOR swizzle: rows x 256 shorts (32 chunks of 8 shorts).
static __device__ __forceinline__ int hsw_chunk(int row, int ks, int quad) {
    int c = ks * 4 + quad;
    int p = c ^ (row & 31);
    return row * 256 + p * 8;
}
static __device__ __forceinline__ int hsw_elem(int row, int col) {
    int p = (col >> 3) ^ (row & 31);
    return row * 256 + p * 8 + (col & 7);
}

// ---------------------------------------------------------------------------
// Fused 3-layer KV MLP — v7b (best measured): weight-resident W1/W2 in
// registers, W3 in 16KB swizzled LDS, 8 waves, 512 blocks.
// Output bf16 [l][b][v][h*32].
// ---------------------------------------------------------------------------
__global__ __launch_bounds__(512, 2) void kv_mfma_kernel(
    const unsigned short* __restrict__ Xbf, const float* __restrict__ true_u,
    const unsigned short* __restrict__ W1t, const unsigned short* __restrict__ W2t,
    const unsigned short* __restrict__ W3t,
    const float* __restrict__ kW1, const float* __restrict__ vW1,
    const float* __restrict__ kb1, const float* __restrict__ kb2, const float* __restrict__ kb3,
    const float* __restrict__ vb1, const float* __restrict__ vb2, const float* __restrict__ vb3,
    unsigned short* __restrict__ keys, unsigned short* __restrict__ vals)
{
    __shared__ unsigned short hbuf[64 * 256];    // 32 KB: X -> h1 -> h2 (swizzled)
    __shared__ unsigned short w3buf[32 * 256];   // 16 KB: W3 slice (swizzled)
    __shared__ float tub[64];                    // true_u tile

    const int tid = threadIdx.x;
    const int w = tid >> 6, lane = tid & 63;
    const int ln = lane & 15, quad = lane >> 4;
    const int lh = blockIdx.y, isv = blockIdx.z;
    const int net = isv * 16 + lh;
    const float* W1f = (isv ? vW1 : kW1) + (size_t)lh * 257 * 256;
    const float* b1  = (isv ? vb1 : kb1) + lh * 256;
    const float* b2  = (isv ? vb2 : kb2) + lh * 256;
    const float* b3  = (isv ? vb3 : kb3) + lh * 32;
    const unsigned short* w1 = W1t + (size_t)net * 65536;
    const unsigned short* w2 = W2t + (size_t)net * 65536;
    const unsigned short* w3 = W3t + (size_t)net * 8192;
    unsigned short* outp = isv ? vals : keys;
    const int base = blockIdx.x * 1024;          // row-group (16 tiles)
    const int cb = w * 32;                       // wave's column base (stages 1-2)

    // ---- one-time: W1/W2 column slices -> registers (32 x 16B loads each) ----
    bf16x8 B1[16], B2[16];
    {
        const unsigned short* p1 = w1 + (size_t)(cb + ln) * 256 + quad * 8;
        const unsigned short* p2 = w2 + (size_t)(cb + ln) * 256 + quad * 8;
        #pragma unroll
        for (int ks = 0; ks < 8; ++ks)
            #pragma unroll
            for (int ct = 0; ct < 2; ++ct) {
                B1[ks * 2 + ct] = *(const bf16x8*)(p1 + (size_t)ct * 16 * 256 + ks * 32);
                B2[ks * 2 + ct] = *(const bf16x8*)(p2 + (size_t)ct * 16 * 256 + ks * 32);
            }
    }
    // ---- one-time: W3 -> swizzled LDS (1024 chunks / 512 threads) ----
    {
        #pragma unroll
        for (int j = 0; j < 2; ++j) {
            const int cidx = tid * 2 + j;
            const int col = cidx >> 5, c = cidx & 31;
            uint4 d = *(const uint4*)(w3 + cidx * 8);
            *(uint4*)&w3buf[col * 256 + (c ^ (col & 31)) * 8] = d;
        }
    }
    // ---- one-time: per-lane epilogue constants ----
    float w1f[2], b1v[2], b2v[2];
    #pragma unroll
    for (int ct = 0; ct < 2; ++ct) {
        const int col = cb + ct * 16 + ln;
        w1f[ct] = W1f[256 * 256 + col];
        b1v[ct] = b1[col];
        b2v[ct] = b2[col];
    }
    const int rt3 = w & 3, ct3 = w >> 2;         // stage-3 tile of this wave
    const float b3v = b3[ct3 * 16 + ln];

    const int b_ = base >> 11;
    const int l_ = lh >> 3, h_ = lh & 7;
    // layout: [l][b][v][h*32 + col]
    unsigned short* ob = outp + (((size_t)l_ * Bc + b_) * Vc) * 256 + h_ * 32;

    const f32x4 zero = {0.f, 0.f, 0.f, 0.f};
    const int xr = tid >> 3, cg = tid & 7;       // X staging: 8 threads/row

    for (int t = 0; t < 16; ++t) {
        const int row0 = base + t * 64;
        __syncthreads();   // prior tile's stage-3 reads complete before X overwrite

        // ---- stage X tile + true_u into LDS ----
        {
            const unsigned short* gx = Xbf + (size_t)(row0 + xr) * 256;
            #pragma unroll
            for (int j = 0; j < 4; ++j) {
                const int c = j * 8 + cg;
                uint4 d = *(const uint4*)(gx + c * 8);
                *(uint4*)&hbuf[xr * 256 + (c ^ (xr & 31)) * 8] = d;
            }
            if (tid < 64) tub[tid] = true_u[row0 + tid];
        }
        __syncthreads();

        // ---- stage 1: h1 = relu(X @ W1 + tu*W1row256 + b1) ----
        f32x4 acc[4][2];
        #pragma unroll
        for (int rt = 0; rt < 4; ++rt)
            #pragma unroll
            for (int ct = 0; ct < 2; ++ct) acc[rt][ct] = zero;
        #pragma unroll
        for (int ks = 0; ks < 8; ++ks) {
            bf16x8 A[4];
            #pragma unroll
            for (int rt = 0; rt < 4; ++rt)
                A[rt] = *(const bf16x8*)&hbuf[hsw_chunk(rt * 16 + ln, ks, quad)];
            #pragma unroll
            for (int rt = 0; rt < 4; ++rt)
                #pragma unroll
                for (int ct = 0; ct < 2; ++ct)
                    acc[rt][ct] = __builtin_amdgcn_mfma_f32_16x16x32_bf16(A[rt], B1[ks * 2 + ct], acc[rt][ct], 0, 0, 0);
        }
        __syncthreads();   // all X reads done before h1 overwrite
        #pragma unroll
        for (int ct = 0; ct < 2; ++ct) {
            const int col = cb + ct * 16 + ln;
            #pragma unroll
            for (int rt = 0; rt < 4; ++rt)
                #pragma unroll
                for (int r = 0; r < 4; ++r) {
                    const int row = rt * 16 + quad * 4 + r;
                    float v = fmaxf(acc[rt][ct][r] + b1v[ct] + tub[row] * w1f[ct], 0.f);
                    hbuf[hsw_elem(row, col)] = f2bf(v);
                }
        }
        __syncthreads();

        // ---- stage 2: h2 = relu(h1 @ W2 + b2) ----
        #pragma unroll
        for (int rt = 0; rt < 4; ++rt)
            #pragma unroll
            for (int ct = 0; ct < 2; ++ct) acc[rt][ct] = zero;
        #pragma unroll
        for (int ks = 0; ks < 8; ++ks) {
            bf16x8 A[4];
            #pragma unroll
            for (int rt = 0; rt < 4; ++rt)
                A[rt] = *(const bf16x8*)&hbuf[hsw_chunk(rt * 16 + ln, ks, quad)];
            #pragma unroll
            for (int rt = 0; rt < 4; ++rt)
                #pragma unroll
                for (int ct = 0; ct < 2; ++ct)
                    acc[rt][ct] = __builtin_amdgcn_mfma_f32_16x16x32_bf16(A[rt], B2[ks * 2 + ct], acc[rt][ct], 0, 0, 0);
        }
        __syncthreads();   // all h1 reads done before h2 overwrite
        #pragma unroll
        for (int ct = 0; ct < 2; ++ct) {
            const int col = cb + ct * 16 + ln;
            #pragma unroll
            for (int rt = 0; rt < 4; ++rt)
                #pragma unroll
                for (int r = 0; r < 4; ++r) {
                    const int row = rt * 16 + quad * 4 + r;
                    hbuf[hsw_elem(row, col)] = f2bf(fmaxf(acc[rt][ct][r] + b2v[ct], 0.f));
                }
        }
        __syncthreads();

        // ---- stage 3: out = h2 @ W3 + b3; wave w -> 16x16 tile (rt3, ct3) ----
        f32x4 acc3 = zero;
        #pragma unroll
        for (int ks = 0; ks < 8; ++ks) {
            bf16x8 A  = *(const bf16x8*)&hbuf[hsw_chunk(rt3 * 16 + ln, ks, quad)];
            bf16x8 Bv = *(const bf16x8*)&w3buf[hsw_chunk(ct3 * 16 + ln, ks, quad)];
            acc3 = __builtin_amdgcn_mfma_f32_16x16x32_bf16(A, Bv, acc3, 0, 0, 0);
        }
        #pragma unroll
        for (int r = 0; r < 4; ++r) {
            const int grow = row0 + rt3 * 16 + quad * 4 + r;
            ob[(size_t)(grow & 2047) * 256 + ct3 * 16 + ln] = f2bf(acc3[r] + b3v);
        }
    }
}

// ---------------------------------------------------------------------------
// ds GEMM: 16 rows/block (256 blocks = 1/CU).
// ---------------------------------------------------------------------------
__global__ __launch_bounds__(256) void ds_gemm_kernel(
    const unsigned short* __restrict__ Abf, const unsigned short* __restrict__ Wt,
    const float* __restrict__ bias, float* __restrict__ outF,
    const int* __restrict__ pp)
{
    const int tid = threadIdx.x;
    const int w = tid >> 6, lane = tid & 63;
    const int ln = lane & 15, quad = lane >> 4;
    const int row0 = blockIdx.x * 16;
    const int cb = w * 64;

    const f32x4 zero = {0.f, 0.f, 0.f, 0.f};
    f32x4 acc[4];
    #pragma unroll
    for (int ct = 0; ct < 4; ++ct) acc[ct] = zero;

    int ra = row0 + ln;
    size_t arow = (size_t)(ra >> 9) * Vc + pp[ra & 511];
    const unsigned short* wb = Wt + (size_t)(cb + ln) * 256 + quad * 8;
    #pragma unroll
    for (int ks = 0; ks < 8; ++ks) {
        bf16x8 A = *(const bf16x8*)(Abf + arow * 256 + ks * 32 + quad * 8);
        #pragma unroll
        for (int ct = 0; ct < 4; ++ct) {
            bf16x8 Bv = *(const bf16x8*)(wb + (size_t)ct * 16 * 256 + ks * 32);
            acc[ct] = __builtin_amdgcn_mfma_f32_16x16x32_bf16(A, Bv, acc[ct], 0, 0, 0);
        }
    }
    #pragma unroll
    for (int ct = 0; ct < 4; ++ct) {
        const int col = cb + ct * 16 + ln;
        const float bb = bias[col];
        #pragma unroll
        for (int r = 0; r < 4; ++r)
            outF[(size_t)(row0 + quad * 4 + r) * 256 + col] = acc[ct][r] + bb;
    }
}

// ---------------------------------------------------------------------------
// Fused attention + residual + LayerNorm1 (PV vectorized, XCD swizzle).
// ---------------------------------------------------------------------------
__global__ __launch_bounds__(512) void attn_ln_kernel(
    const unsigned short* __restrict__ keys, const unsigned short* __restrict__ vals,
    const int* __restrict__ nbr, const float* __restrict__ mask,
    const float* __restrict__ g, const float* __restrict__ be,
    float* __restrict__ AV, unsigned short* __restrict__ AVbf, const int l)
{
    __shared__ float qs[256];
    __shared__ float wts[8 * 64];
    __shared__ float att_s[256];
    __shared__ int ni[64];
    __shared__ float red[4], red2[4];

    const int bid = blockIdx.x;
    const int row = ((bid & 7) << 9) | (bid >> 3);   // b = bid&7, p = bid>>3
    const int b = row >> 9, p = row & 511;
    const int tid = threadIdx.x;
    const int h = tid >> 6, n = tid & 63;

    if (tid < 256) qs[tid] = AV[(size_t)row * 256 + tid];
    if (tid < 64)  ni[tid] = nbr[p * 64 + tid];
    __syncthreads();

    const unsigned short* kvbase = keys + (((size_t)l * Bc + b) * Vc) * 256;
    const unsigned short* vvbase = vals + (((size_t)l * Bc + b) * Vc) * 256;

    // phase 1: scores + softmax (per head-wave)
    {
        const int vi = ni[n];
        const unsigned short* kp = kvbase + (size_t)vi * 256 + h * 32;
        const float* qh = qs + h * 32;
        float s = 0.f;
        #pragma unroll
        for (int j = 0; j < 4; ++j) {
            uint4 u = *(const uint4*)(kp + j * 8);
            const float* q = qh + j * 8;
            s += q[0] * bflo(u.x) + q[1] * bfhi(u.x);
            s += q[2] * bflo(u.y) + q[3] * bfhi(u.y);
            s += q[4] * bflo(u.z) + q[5] * bfhi(u.z);
            s += q[6] * bflo(u.w) + q[7] * bfhi(u.w);
        }
        s = (s - mask[p * 64 + n]) * 0.17677669529663689f;  // AD^-0.5
        float mx = s;
        #pragma unroll
        for (int off = 32; off >= 1; off >>= 1) mx = fmaxf(mx, __shfl_xor(mx, off));
        float e = expf(s - mx);
        float sum = e;
        #pragma unroll
        for (int off = 32; off >= 1; off >>= 1) sum += __shfl_xor(sum, off);
        wts[h * 64 + n] = e / sum;   // same-wave producer/consumer, no barrier
    }

    // phase 2: PV vectorized. lane: nb4 = n>>2 (nbr group), cg8 = (n&3)*8.
    {
        const int nb4 = n >> 2, cg8 = (n & 3) * 8;
        float a[8];
        #pragma unroll
        for (int j = 0; j < 8; ++j) a[j] = 0.f;
        #pragma unroll
        for (int pass = 0; pass < 4; ++pass) {
            const int nn = pass * 16 + nb4;
            const float wgt = wts[h * 64 + nn];
            const unsigned short* vp = vvbase + (size_t)ni[nn] * 256 + h * 32 + cg8;
            uint4 u = *(const uint4*)vp;
            a[0] += wgt * bflo(u.x); a[1] += wgt * bfhi(u.x);
            a[2] += wgt * bflo(u.y); a[3] += wgt * bfhi(u.y);
            a[4] += wgt * bflo(u.z); a[5] += wgt * bfhi(u.z);
            a[6] += wgt * bflo(u.w); a[7] += wgt * bfhi(u.w);
        }
        #pragma unroll
        for (int off = 4; off <= 32; off <<= 1)
            #pragma unroll
            for (int j = 0; j < 8; ++j)
                a[j] += __shfl_xor(a[j], off);
        if (nb4 == 0)
            #pragma unroll
            for (int j = 0; j < 8; ++j)
                att_s[h * 32 + cg8 + j] = a[j];
    }
    __syncthreads();

    // phase 3: LN(AV + att) over 256 (first 4 waves carry data)
    float x = 0.f;
    if (tid < 256) x = qs[tid] + att_s[tid];
    float s = x;
    #pragma unroll
    for (int off = 32; off >= 1; off >>= 1) s += __shfl_xor(s, off);
    if ((tid & 63) == 0 && tid < 256) red[tid >> 6] = s;
    __syncthreads();
    const float mu = (red[0] + red[1] + red[2] + red[3]) * (1.0f / 256.0f);
    const float dx = x - mu;
    float v = dx * dx;
    #pragma unroll
    for (int off = 32; off >= 1; off >>= 1) v += __shfl_xor(v, off);
    if ((tid & 63) == 0 && tid < 256) red2[tid >> 6] = v;
    __syncthreads();
    if (tid < 256) {
        const float var = (red2[0] + red2[1] + red2[2] + red2[3]) * (1.0f / 256.0f);
        float o = dx * (1.0f / sqrtf(var + 1e-5f)) * g[tid] + be[tid];
        AV[(size_t)row * 256 + tid] = o;
        AVbf[(size_t)row * 256 + tid] = f2bf(o);
    }
}

// ---------------------------------------------------------------------------
// Fused FF block: 16 rows/block (256 blocks = 1/CU).
// AV = LN2(AV + relu(AVbf@W1+b1)@W2 + b2) -> AV fp32 + AVbf.
// ---------------------------------------------------------------------------
__global__ __launch_bounds__(256) void ff_fused_kernel(
    const unsigned short* __restrict__ Abf, const float* __restrict__ resF,
    const unsigned short* __restrict__ W1t, const float* __restrict__ b1,
    const unsigned short* __restrict__ W2t, const float* __restrict__ b2,
    const float* __restrict__ g, const float* __restrict__ be,
    float* __restrict__ outF, unsigned short* __restrict__ outB)
{
    __shared__ unsigned short hbuf[16 * 256];   // 8 KB
    __shared__ float psum[16][4], psq[16][4];

    const int tid = threadIdx.x;
    const int w = tid >> 6, lane = tid & 63;
    const int ln = lane & 15, quad = lane >> 4;
    const int row0 = blockIdx.x * 16;
    const int cb = w * 64;

    const f32x4 zero = {0.f, 0.f, 0.f, 0.f};
    f32x4 acc[4];

    // ---- stage A: T1 = relu(A@W1 + b1) -> hbuf ----
    #pragma unroll
    for (int ct = 0; ct < 4; ++ct) acc[ct] = zero;
    {
        const unsigned short* ab = Abf + ((size_t)row0 + ln) * 256 + quad * 8;
        const unsigned short* wb = W1t + (size_t)(cb + ln) * 256 + quad * 8;
        #pragma unroll
        for (int ks = 0; ks < 8; ++ks) {
            bf16x8 A = *(const bf16x8*)(ab + ks * 32);
            #pragma unroll
            for (int ct = 0; ct < 4; ++ct) {
                bf16x8 Bv = *(const bf16x8*)(wb + (size_t)ct * 16 * 256 + ks * 32);
                acc[ct] = __builtin_amdgcn_mfma_f32_16x16x32_bf16(A, Bv, acc[ct], 0, 0, 0);
            }
        }
    }
    #pragma unroll
    for (int ct = 0; ct < 4; ++ct) {
        const int col = cb + ct * 16 + ln;
        const float bb = b1[col];
        #pragma unroll
        for (int r = 0; r < 4; ++r) {
            const int row = quad * 4 + r;
            hbuf[hsw_elem(row, col)] = f2bf(fmaxf(acc[ct][r] + bb, 0.f));
        }
    }
    __syncthreads();

    // ---- stage B: T2 = T1@W2 + b2 (+ residual) ----
    #pragma unroll
    for (int ct = 0; ct < 4; ++ct) acc[ct] = zero;
    {
        const unsigned short* wb = W2t + (size_t)(cb + ln) * 256 + quad * 8;
        #pragma unroll
        for (int ks = 0; ks < 8; ++ks) {
            bf16x8 A = *(const bf16x8*)&hbuf[hsw_chunk(ln, ks, quad)];
            #pragma unroll
            for (int ct = 0; ct < 4; ++ct) {
                bf16x8 Bv = *(const bf16x8*)(wb + (size_t)ct * 16 * 256 + ks * 32);
                acc[ct] = __builtin_amdgcn_mfma_f32_16x16x32_bf16(A, Bv, acc[ct], 0, 0, 0);
            }
        }
    }
    // v = T2 + b2 + residual; per-wave partial sums for LN
    float vv[4][4];
    #pragma unroll
    for (int ct = 0; ct < 4; ++ct) {
        const int col = cb + ct * 16 + ln;
        const float bb = b2[col];
        #pragma unroll
        for (int r = 0; r < 4; ++r) {
            const int row = quad * 4 + r;
            float res = resF[(size_t)(row0 + row) * 256 + col];
            vv[ct][r] = acc[ct][r] + bb + res;
        }
    }
    #pragma unroll
    for (int r = 0; r < 4; ++r) {
        float sl = 0.f, ql = 0.f;
        #pragma unroll
        for (int ct = 0; ct < 4; ++ct) { float t = vv[ct][r]; sl += t; ql += t * t; }
        #pragma unroll
        for (int off = 8; off >= 1; off >>= 1) {
            sl += __shfl_xor(sl, off);
            ql += __shfl_xor(ql, off);
        }
        if (ln == 0) {
            const int row = quad * 4 + r;
            psum[row][w] = sl; psq[row][w] = ql;
        }
    }
    __syncthreads();

    // ---- LN epilogue ----
    #pragma unroll
    for (int r = 0; r < 4; ++r) {
        const int row = quad * 4 + r;
        const float mu = (psum[row][0] + psum[row][1] + psum[row][2] + psum[row][3]) * (1.0f / 256.0f);
        const float eq = (psq[row][0] + psq[row][1] + psq[row][2] + psq[row][3]) * (1.0f / 256.0f);
        const float rstd = 1.0f / sqrtf(fmaxf(eq - mu * mu, 0.f) + 1e-5f);
        #pragma unroll
        for (int ct = 0; ct < 4; ++ct) {
            const int col = cb + ct * 16 + ln;
            float o = (vv[ct][r] - mu) * rstd * g[col] + be[col];
            outF[(size_t)(row0 + row) * 256 + col] = o;
            outB[(size_t)(row0 + row) * 256 + col] = f2bf(o);
        }
    }
}

// ---------------------------------------------------------------------------
// Fused decoder + loss: 16 rows/block (256 blocks = 1/CU).
// ---------------------------------------------------------------------------
__global__ __launch_bounds__(256) void de_loss_kernel(
    const unsigned short* __restrict__ Abf,
    const unsigned short* __restrict__ W1t, const float* __restrict__ b1,
    const unsigned short* __restrict__ W2t, const float* __restrict__ b2,
    const unsigned short* __restrict__ W3t, const float* __restrict__ b3,
    const float* __restrict__ true_u, const int* __restrict__ pp,
    float* __restrict__ outp)
{
    __shared__ unsigned short hbuf[16 * 256];   // 8 KB
    __shared__ float pmax[16][4], psum[16][4], pxt[16][4];
    __shared__ float rowmax[16];
    __shared__ int tcol[16];

    const int tid = threadIdx.x;
    const int w = tid >> 6, lane = tid & 63;
    const int ln = lane & 15, quad = lane >> 4;
    const int row0 = blockIdx.x * 16;
    const int b = row0 >> 9;

    const f32x4 zero = {0.f, 0.f, 0.f, 0.f};
    f32x4 acc[4];

    // ---- stage 1: h1 ----
    #pragma unroll
    for (int ct = 0; ct < 4; ++ct) acc[ct] = zero;
    {
        const unsigned short* ab = Abf + ((size_t)row0 + ln) * 256 + quad * 8;
        const unsigned short* wb = W1t + (size_t)(w * 64 + ln) * 256 + quad * 8;
        #pragma unroll
        for (int ks = 0; ks < 8; ++ks) {
            bf16x8 A = *(const bf16x8*)(ab + ks * 32);
            #pragma unroll
            for (int ct = 0; ct < 4; ++ct) {
                bf16x8 Bv = *(const bf16x8*)(wb + (size_t)ct * 16 * 256 + ks * 32);
                acc[ct] = __builtin_amdgcn_mfma_f32_16x16x32_bf16(A, Bv, acc[ct], 0, 0, 0);
            }
        }
    }
    #pragma unroll
    for (int ct = 0; ct < 4; ++ct) {
        const int col = w * 64 + ct * 16 + ln;
        const float bb = b1[col];
        #pragma unroll
        for (int r = 0; r < 4; ++r) {
            const int row = quad * 4 + r;
            hbuf[hsw_elem(row, col)] = f2bf(fmaxf(acc[ct][r] + bb, 0.f));
        }
    }
    __syncthreads();

    // ---- stage 2: h2 ----
    #pragma unroll
    for (int ct = 0; ct < 4; ++ct) acc[ct] = zero;
    {
        const unsigned short* wb = W2t + (size_t)(w * 64 + ln) * 256 + quad * 8;
        #pragma unroll
        for (int ks = 0; ks < 8; ++ks) {
            bf16x8 A = *(const bf16x8*)&hbuf[hsw_chunk(ln, ks, quad)];
            #pragma unroll
            for (int ct = 0; ct < 4; ++ct) {
                bf16x8 Bv = *(const bf16x8*)(wb + (size_t)ct * 16 * 256 + ks * 32);
                acc[ct] = __builtin_amdgcn_mfma_f32_16x16x32_bf16(A, Bv, acc[ct], 0, 0, 0);
            }
        }
    }
    __syncthreads();
    #pragma unroll
    for (int ct = 0; ct < 4; ++ct) {
        const int col = w * 64 + ct * 16 + ln;
        const float bb = b2[col];
        #pragma unroll
        for (int r = 0; r < 4; ++r) {
            const int row = quad * 4 + r;
            hbuf[hsw_elem(row, col)] = f2bf(fmaxf(acc[ct][r] + bb, 0.f));
        }
    }
    __syncthreads();

    // ---- stage 3: logits (128 cols; wave w -> cols w*32..+31) ----
    const int cb3 = w * 32;
    f32x4 a3[2];
    a3[0] = zero; a3[1] = zero;
    #pragma unroll
    for (int ks = 0; ks < 8; ++ks) {
        bf16x8 A = *(const bf16x8*)&hbuf[hsw_chunk(ln, ks, quad)];
        #pragma unroll
        for (int ct = 0; ct < 2; ++ct) {
            bf16x8 Bv = *(const bf16x8*)(W3t + (size_t)(cb3 + ct * 16 + ln) * 256 + ks * 32 + quad * 8);
            a3[ct] = __builtin_amdgcn_mfma_f32_16x16x32_bf16(A, Bv, a3[ct], 0, 0, 0);
        }
    }
    float lg[2][4];
    #pragma unroll
    for (int ct = 0; ct < 2; ++ct) {
        const float bb = b3[cb3 + ct * 16 + ln];
        #pragma unroll
        for (int r = 0; r < 4; ++r) lg[ct][r] = a3[ct][r] + bb;
    }

    // per-wave row-max partials
    #pragma unroll
    for (int r = 0; r < 4; ++r) {
        float m = fmaxf(lg[0][r], lg[1][r]);
        #pragma unroll
        for (int off = 8; off >= 1; off >>= 1) m = fmaxf(m, __shfl_xor(m, off));
        if (ln == 0) pmax[quad * 4 + r][w] = m;
    }
    __syncthreads();
    if (tid < 16) {
        const int grow = row0 + tid;
        rowmax[tid] = fmaxf(fmaxf(pmax[tid][0], pmax[tid][1]), fmaxf(pmax[tid][2], pmax[tid][3]));
        float tu = true_u[(size_t)(grow >> 9) * Vc + pp[grow & 511]];
        int t = (int)floorf(tu * 128.0f);
        tcol[tid] = t < 0 ? 0 : (t > 127 ? 127 : t);
    }
    __syncthreads();
    // per-wave sum-exp and target-pick partials
    #pragma unroll
    for (int r = 0; r < 4; ++r) {
        const int row = quad * 4 + r;
        const float mx = rowmax[row];
        const int t = tcol[row];
        float e = expf(lg[0][r] - mx) + expf(lg[1][r] - mx);
        float xt = ((cb3 + ln) == t ? lg[0][r] : 0.f) +
                   ((cb3 + 16 + ln) == t ? lg[1][r] : 0.f);
        #pragma unroll
        for (int off = 8; off >= 1; off >>= 1) {
            e += __shfl_xor(e, off);
            xt += __shfl_xor(xt, off);
        }
        if (ln == 0) { psum[row][w] = e; pxt[row][w] = xt; }
    }
    __syncthreads();
    // final: rows handled by lanes 0..15 of wave 0, reduce, one atomic
    float contrib = 0.f;
    if (tid < 16) {
        const float sum = psum[tid][0] + psum[tid][1] + psum[tid][2] + psum[tid][3];
        const float xt  = pxt[tid][0] + pxt[tid][1] + pxt[tid][2] + pxt[tid][3];
        const float lp = logf(128.0f) + (xt - rowmax[tid]) - logf(sum);
        contrib = -lp;
    }
    if (w == 0) {
        #pragma unroll
        for (int off = 32; off >= 1; off >>= 1) contrib += __shfl_xor(contrib, off);
        if (lane == 0) atomicAdd(&outp[b], contrib);
    }
}

// ---------------------------------------------------------------------------
extern "C" void kernel_launch(void* const* d_in, const int* in_sizes, int n_in,
                              void* d_out, int out_size, void* d_ws, size_t ws_size,
                              hipStream_t stream)
{
    (void)in_sizes; (void)n_in; (void)out_size; (void)ws_size;

    const float* encoded        = (const float*)d_in[0];
    const float* true_u         = (const float*)d_in[1];
    const float* attn_mask      = (const float*)d_in[2];
    const int*   pred_points    = (const int*)d_in[3];
    const int*   neighbor_index = (const int*)d_in[4];
    const float* kW1 = (const float*)d_in[5];
    const float* kb1 = (const float*)d_in[6];
    const float* kW2 = (const float*)d_in[7];
    const float* kb2 = (const float*)d_in[8];
    const float* kW3 = (const float*)d_in[9];
    const float* kb3 = (const float*)d_in[10];
    const float* vW1 = (const float*)d_in[11];
    const float* vb1 = (const float*)d_in[12];
    const float* vW2 = (const float*)d_in[13];
    const float* vb2 = (const float*)d_in[14];
    const float* vW3 = (const float*)d_in[15];
    const float* vb3 = (const float*)d_in[16];
    const float* ds_W  = (const float*)d_in[17];
    const float* ds_b  = (const float*)d_in[18];
    const float* ln1_g = (const float*)d_in[19];
    const float* ln1_b = (const float*)d_in[20];
    const float* ff_W1 = (const float*)d_in[21];
    const float* ff_b1 = (const float*)d_in[22];
    const float* ff_W2 = (const float*)d_in[23];
    const float* ff_b2 = (const float*)d_in[24];
    const float* ln2_g = (const float*)d_in[25];
    const float* ln2_b = (const float*)d_in[26];
    const float* de_W1 = (const float*)d_in[27];
    const float* de_b1 = (const float*)d_in[28];
    const float* de_W2 = (const float*)d_in[29];
    const float* de_b2 = (const float*)d_in[30];
    const float* de_W3 = (const float*)d_in[31];
    const float* de_b3 = (const float*)d_in[32];

    float* out = (float*)d_out;

    // workspace layout
    constexpr size_t KV_ELEMS = (size_t)Lc * Bc * Hc * Vc * 32;  // 8,388,608
    unsigned short* keys = (unsigned short*)d_ws;            // bf16 [l][b][v][256]
    unsigned short* vals = keys + KV_ELEMS;
    float* AV = (float*)(vals + KV_ELEMS);                   // 4096 x 256 f32
    unsigned short* Xbf  = (unsigned short*)(AV + (size_t)ROWS_AT * 256);
    unsigned short* W1t  = Xbf + (size_t)ROWS_KV * 256;      // 32 nets x [256][256]
    unsigned short* W2t  = W1t + (size_t)32 * 65536;
    unsigned short* W3t  = W2t + (size_t)32 * 65536;         // 32 nets x [32][256]
    unsigned short* Wm   = W3t + (size_t)32 * 8192;          // 8 slots x 65536
    unsigned short* AVbf = Wm + (size_t)8 * 65536;           // 4096 x 256 bf16

    (void)hipMemsetAsync(out, 0, Bc * sizeof(float), stream);

    // prep (2 launches)
    conv_x_kernel<<<dim3(ROWS_KV * 256 / 4 / 256), 256, 0, stream>>>(encoded, Xbf);
    transpose_all_kernel<<<dim3(8, 8, 104), 256, 0, stream>>>(
        kW1, vW1, kW2, vW2, kW3, vW3,
        ds_W, ff_W1, ff_W2, de_W1, de_W2, de_W3,
        W1t, W2t, W3t, Wm);
    // misc slots: 0=ds 1=ffW1_0 2=ffW1_1 3=ffW2_0 4=ffW2_1 5=deW1 6=deW2 7=deW3

    // KV MLPs v7b: 16 rg x 16 (l,h) x {k,v}
    kv_mfma_kernel<<<dim3(16, 16, 2), 512, 0, stream>>>(
        Xbf, true_u, W1t, W2t, W3t, kW1, vW1,
        kb1, kb2, kb3, vb1, vb2, vb3, keys, vals);

    // att_value = encoded[:,pred_points,:] @ ds_W + ds_b
    ds_gemm_kernel<<<dim3(ROWS_AT / 16), 256, 0, stream>>>(
        Xbf, Wm + (size_t)0 * 65536, ds_b, AV, pred_points);

    for (int l = 0; l < Lc; ++l) {
        attn_ln_kernel<<<dim3(ROWS_AT), 512, 0, stream>>>(
            keys, vals, neighbor_index, attn_mask,
            ln1_g + l * 256, ln1_b + l * 256, AV, AVbf, l);
        ff_fused_kernel<<<dim3(ROWS_AT / 16), 256, 0, stream>>>(
            AVbf, AV,
            Wm + (size_t)(1 + l) * 65536, ff_b1 + l * 256,
            Wm + (size_t)(3 + l) * 65536, ff_b2 + l * 256,
            ln2_g + l * 256, ln2_b + l * 256, AV, AVbf);
    }

    de_loss_kernel<<<dim3(ROWS_AT / 16), 256, 0, stream>>>(
        AVbf,
        Wm + (size_t)5 * 65536, de_b1,
        Wm + (size_t)6 * 65536, de_b2,
        Wm + (size_t)7 * 65536, de_b3,
        true_u, pred_points, out);
}

// Round 16
// 464.944 us; speedup vs baseline: 1.1373x; 1.0210x over previous
//
#include <hip/hip_runtime.h>
#include <hip/hip_bf16.h>
#include <cstdint>
#include <cstddef>

// Problem dims (compile-time)
constexpr int Bc = 8;
constexpr int Vc = 2048;   // S*T
constexpr int Pc = 512;
constexpr int Hc = 8;
constexpr int Lc = 2;
constexpr int ROWS_KV = Bc * Vc;   // 16384
constexpr int ROWS_AT = Bc * Pc;   // 4096

typedef __attribute__((ext_vector_type(8))) short bf16x8;   // 8 bf16 (4 VGPRs)
typedef __attribute__((ext_vector_type(4))) float f32x4;

static __device__ __forceinline__ unsigned short f2bf(float v) {
    __hip_bfloat16 h = __float2bfloat16(v);
    return *(unsigned short*)&h;
}
static __device__ __forceinline__ float bflo(unsigned int u) {
    return __uint_as_float(u << 16);
}
static __device__ __forceinline__ float bfhi(unsigned int u) {
    return __uint_as_float(u & 0xffff0000u);
}

// ---------------------------------------------------------------------------
// Prep: encoded fp32 -> bf16 (row-major [16384][256])
// ---------------------------------------------------------------------------
__global__ __launch_bounds__(256) void conv_x_kernel(
    const float* __restrict__ x, unsigned short* __restrict__ xb)
{
    const int i = blockIdx.x * 256 + threadIdx.x;   // 1 float4 per thread
    float4 v = ((const float4*)x)[i];
    ushort4 o;
    o.x = f2bf(v.x); o.y = f2bf(v.y); o.z = f2bf(v.z); o.w = f2bf(v.w);
    ((ushort4*)xb)[i] = o;
}

// ---------------------------------------------------------------------------
// Merged prep: all weight transposes [K x C] fp32 -> [C x 256] bf16.
// ---------------------------------------------------------------------------
__global__ __launch_bounds__(256) void transpose_all_kernel(
    const float* kW1, const float* vW1, const float* kW2, const float* vW2,
    const float* kW3, const float* vW3,
    const float* ds_W, const float* ff_W1, const float* ff_W2,
    const float* de_W1, const float* de_W2, const float* de_W3,
    unsigned short* __restrict__ W1t, unsigned short* __restrict__ W2t,
    unsigned short* __restrict__ W3t, unsigned short* __restrict__ Wm)
{
    const int z = blockIdx.z;
    const float* src;
    unsigned short* dst;
    int C;
    if (z < 32) {
        const int net = z;
        src = ((net >> 4) ? vW1 : kW1) + (size_t)(net & 15) * 257 * 256;
        dst = W1t + (size_t)net * 65536;
        C = 256;
    } else if (z < 64) {
        const int net = z - 32;
        src = ((net >> 4) ? vW2 : kW2) + (size_t)(net & 15) * 256 * 256;
        dst = W2t + (size_t)net * 65536;
        C = 256;
    } else if (z < 96) {
        const int net = z - 64;
        src = ((net >> 4) ? vW3 : kW3) + (size_t)(net & 15) * 256 * 32;
        dst = W3t + (size_t)net * 8192;
        C = 32;
    } else {
        const int id = z - 96;
        const float* srcs[8] = {ds_W, ff_W1, ff_W1 + (size_t)65536,
                                ff_W2, ff_W2 + (size_t)65536, de_W1, de_W2, de_W3};
        src = srcs[id];
        dst = Wm + (size_t)id * 65536;
        C = (id == 7) ? 128 : 256;
    }
    if (blockIdx.x * 32 >= C) return;
    __shared__ float t[32][33];
    const int c0 = blockIdx.x * 32, k0 = blockIdx.y * 32;
    const int tx = threadIdx.x & 31, ty = threadIdx.x >> 5;
    #pragma unroll
    for (int i = 0; i < 32; i += 8)
        t[ty + i][tx] = src[(size_t)(k0 + ty + i) * C + (c0 + tx)];
    __syncthreads();
    #pragma unroll
    for (int i = 0; i < 32; i += 8)
        dst[(size_t)(c0 + ty + i) * 256 + (k0 + tx)] = f2bf(t[tx][ty + i]);
}

// h-buf XOR swizzle: rows x 256 shorts (32 chunks of 8 shorts).
static __device__ __forceinline__ int hsw_chunk(int row, int ks, int quad) {
    int c = ks * 4 + quad;
    int p = c ^ (row & 31);
    return row * 256 + p * 8;
}
static __device__ __forceinline__ int hsw_elem(int row, int col) {
    int p = (col >> 3) ^ (row & 31);
    return row * 256 + p * 8 + (col & 7);
}

// ---------------------------------------------------------------------------
// Fused 3-layer KV MLP — v7b (best measured): weight-resident W1/W2 in
// registers, W3 in 16KB swizzled LDS, 8 waves, 512 blocks.
// Output bf16 [l][b][v][h*32].
// ---------------------------------------------------------------------------
__global__ __launch_bounds__(512, 2) void kv_mfma_kernel(
    const unsigned short* __restrict__ Xbf, const float* __restrict__ true_u,
    const unsigned short* __restrict__ W1t, const unsigned short* __restrict__ W2t,
    const unsigned short* __restrict__ W3t,
    const float* __restrict__ kW1, const float* __restrict__ vW1,
    const float* __restrict__ kb1, const float* __restrict__ kb2, const float* __restrict__ kb3,
    const float* __restrict__ vb1, const float* __restrict__ vb2, const float* __restrict__ vb3,
    unsigned short* __restrict__ keys, unsigned short* __restrict__ vals)
{
    __shared__ unsigned short hbuf[64 * 256];    // 32 KB: X -> h1 -> h2 (swizzled)
    __shared__ unsigned short w3buf[32 * 256];   // 16 KB: W3 slice (swizzled)
    __shared__ float tub[64];                    // true_u tile

    const int tid = threadIdx.x;
    const int w = tid >> 6, lane = tid & 63;
    const int ln = lane & 15, quad = lane >> 4;
    const int lh = blockIdx.y, isv = blockIdx.z;
    const int net = isv * 16 + lh;
    const float* W1f = (isv ? vW1 : kW1) + (size_t)lh * 257 * 256;
    const float* b1  = (isv ? vb1 : kb1) + lh * 256;
    const float* b2  = (isv ? vb2 : kb2) + lh * 256;
    const float* b3  = (isv ? vb3 : kb3) + lh * 32;
    const unsigned short* w1 = W1t + (size_t)net * 65536;
    const unsigned short* w2 = W2t + (size_t)net * 65536;
    const unsigned short* w3 = W3t + (size_t)net * 8192;
    unsigned short* outp = isv ? vals : keys;
    const int base = blockIdx.x * 1024;          // row-group (16 tiles)
    const int cb = w * 32;                       // wave's column base (stages 1-2)

    // ---- one-time: W1/W2 column slices -> registers ----
    bf16x8 B1[16], B2[16];
    {
        const unsigned short* p1 = w1 + (size_t)(cb + ln) * 256 + quad * 8;
        const unsigned short* p2 = w2 + (size_t)(cb + ln) * 256 + quad * 8;
        #pragma unroll
        for (int ks = 0; ks < 8; ++ks)
            #pragma unroll
            for (int ct = 0; ct < 2; ++ct) {
                B1[ks * 2 + ct] = *(const bf16x8*)(p1 + (size_t)ct * 16 * 256 + ks * 32);
                B2[ks * 2 + ct] = *(const bf16x8*)(p2 + (size_t)ct * 16 * 256 + ks * 32);
            }
    }
    // ---- one-time: W3 -> swizzled LDS ----
    {
        #pragma unroll
        for (int j = 0; j < 2; ++j) {
            const int cidx = tid * 2 + j;
            const int col = cidx >> 5, c = cidx & 31;
            uint4 d = *(const uint4*)(w3 + cidx * 8);
            *(uint4*)&w3buf[col * 256 + (c ^ (col & 31)) * 8] = d;
        }
    }
    float w1f[2], b1v[2], b2v[2];
    #pragma unroll
    for (int ct = 0; ct < 2; ++ct) {
        const int col = cb + ct * 16 + ln;
        w1f[ct] = W1f[256 * 256 + col];
        b1v[ct] = b1[col];
        b2v[ct] = b2[col];
    }
    const int rt3 = w & 3, ct3 = w >> 2;
    const float b3v = b3[ct3 * 16 + ln];

    const int b_ = base >> 11;
    const int l_ = lh >> 3, h_ = lh & 7;
    unsigned short* ob = outp + (((size_t)l_ * Bc + b_) * Vc) * 256 + h_ * 32;

    const f32x4 zero = {0.f, 0.f, 0.f, 0.f};
    const int xr = tid >> 3, cg = tid & 7;

    for (int t = 0; t < 16; ++t) {
        const int row0 = base + t * 64;
        __syncthreads();

        {
            const unsigned short* gx = Xbf + (size_t)(row0 + xr) * 256;
            #pragma unroll
            for (int j = 0; j < 4; ++j) {
                const int c = j * 8 + cg;
                uint4 d = *(const uint4*)(gx + c * 8);
                *(uint4*)&hbuf[xr * 256 + (c ^ (xr & 31)) * 8] = d;
            }
            if (tid < 64) tub[tid] = true_u[row0 + tid];
        }
        __syncthreads();

        // ---- stage 1 ----
        f32x4 acc[4][2];
        #pragma unroll
        for (int rt = 0; rt < 4; ++rt)
            #pragma unroll
            for (int ct = 0; ct < 2; ++ct) acc[rt][ct] = zero;
        #pragma unroll
        for (int ks = 0; ks < 8; ++ks) {
            bf16x8 A[4];
            #pragma unroll
            for (int rt = 0; rt < 4; ++rt)
                A[rt] = *(const bf16x8*)&hbuf[hsw_chunk(rt * 16 + ln, ks, quad)];
            #pragma unroll
            for (int rt = 0; rt < 4; ++rt)
                #pragma unroll
                for (int ct = 0; ct < 2; ++ct)
                    acc[rt][ct] = __builtin_amdgcn_mfma_f32_16x16x32_bf16(A[rt], B1[ks * 2 + ct], acc[rt][ct], 0, 0, 0);
        }
        __syncthreads();
        #pragma unroll
        for (int ct = 0; ct < 2; ++ct) {
            const int col = cb + ct * 16 + ln;
            #pragma unroll
            for (int rt = 0; rt < 4; ++rt)
                #pragma unroll
                for (int r = 0; r < 4; ++r) {
                    const int row = rt * 16 + quad * 4 + r;
                    float v = fmaxf(acc[rt][ct][r] + b1v[ct] + tub[row] * w1f[ct], 0.f);
                    hbuf[hsw_elem(row, col)] = f2bf(v);
                }
        }
        __syncthreads();

        // ---- stage 2 ----
        #pragma unroll
        for (int rt = 0; rt < 4; ++rt)
            #pragma unroll
            for (int ct = 0; ct < 2; ++ct) acc[rt][ct] = zero;
        #pragma unroll
        for (int ks = 0; ks < 8; ++ks) {
            bf16x8 A[4];
            #pragma unroll
            for (int rt = 0; rt < 4; ++rt)
                A[rt] = *(const bf16x8*)&hbuf[hsw_chunk(rt * 16 + ln, ks, quad)];
            #pragma unroll
            for (int rt = 0; rt < 4; ++rt)
                #pragma unroll
                for (int ct = 0; ct < 2; ++ct)
                    acc[rt][ct] = __builtin_amdgcn_mfma_f32_16x16x32_bf16(A[rt], B2[ks * 2 + ct], acc[rt][ct], 0, 0, 0);
        }
        __syncthreads();
        #pragma unroll
        for (int ct = 0; ct < 2; ++ct) {
            const int col = cb + ct * 16 + ln;
            #pragma unroll
            for (int rt = 0; rt < 4; ++rt)
                #pragma unroll
                for (int r = 0; r < 4; ++r) {
                    const int row = rt * 16 + quad * 4 + r;
                    hbuf[hsw_elem(row, col)] = f2bf(fmaxf(acc[rt][ct][r] + b2v[ct], 0.f));
                }
        }
        __syncthreads();

        // ---- stage 3 ----
        f32x4 acc3 = zero;
        #pragma unroll
        for (int ks = 0; ks < 8; ++ks) {
            bf16x8 A  = *(const bf16x8*)&hbuf[hsw_chunk(rt3 * 16 + ln, ks, quad)];
            bf16x8 Bv = *(const bf16x8*)&w3buf[hsw_chunk(ct3 * 16 + ln, ks, quad)];
            acc3 = __builtin_amdgcn_mfma_f32_16x16x32_bf16(A, Bv, acc3, 0, 0, 0);
        }
        #pragma unroll
        for (int r = 0; r < 4; ++r) {
            const int grow = row0 + rt3 * 16 + quad * 4 + r;
            ob[(size_t)(grow & 2047) * 256 + ct3 * 16 + ln] = f2bf(acc3[r] + b3v);
        }
    }
}

// ---------------------------------------------------------------------------
// FUSED TAIL: per block = 16 rows (one batch b), 512 threads (8 waves).
// ds GEMM -> [attn -> LN1 -> ff1 -> ff2 -> LN2] x2 -> de1 -> de2 -> de3+loss.
// All intermediates in LDS; weights streamed from L2.
// GEMM stages: wave w owns cols w*32 (2 col-tiles); rows = one 16-row tile.
// Attention: wave w owns rows w*2, w*2+1 (8 heads each, phase1+PV in-wave).
// ---------------------------------------------------------------------------
__global__ __launch_bounds__(512) void decoder_kernel(
    const unsigned short* __restrict__ Xbf, const float* __restrict__ true_u,
    const unsigned short* __restrict__ keys, const unsigned short* __restrict__ vals,
    const int* __restrict__ nbr, const float* __restrict__ mask,
    const int* __restrict__ pp, const unsigned short* __restrict__ Wm,
    const float* __restrict__ ds_b,
    const float* __restrict__ ln1_g, const float* __restrict__ ln1_b,
    const float* __restrict__ ff_b1, const float* __restrict__ ff_b2,
    const float* __restrict__ ln2_g, const float* __restrict__ ln2_b,
    const float* __restrict__ de_b1, const float* __restrict__ de_b2,
    const float* __restrict__ de_b3, float* __restrict__ outp)
{
    __shared__ float avF[16][264];              // activation fp32 (residual/q)
    __shared__ float attF[16][264];             // attention output fp32
    __shared__ unsigned short abuf[16 * 256];   // activation bf16 (swizzled)
    __shared__ unsigned short hbuf[16 * 256];   // GEMM intermediate (swizzled)
    __shared__ int   ni_s[16][64];
    __shared__ float wtsb[8][64];
    __shared__ float psum[16][8], psq[16][8];
    __shared__ float rowmax[16];
    __shared__ int   tcol[16];
    __shared__ int   pps[16];

    const int tid = threadIdx.x;
    const int w = tid >> 6, lane = tid & 63;
    const int ln = lane & 15, quad = lane >> 4;
    const int bid = blockIdx.x;
    const int b = bid & 7;                       // XCD-affine batch
    const int r0 = b * 512 + (bid >> 3) * 16;    // global row base
    const int cb = w * 32;                       // GEMM column base

    const f32x4 zero = {0.f, 0.f, 0.f, 0.f};

    // ---- init: pp values + neighbor indices ----
    if (tid < 16) pps[tid] = pp[(r0 + tid) & 511];
    #pragma unroll
    for (int j = 0; j < 2; ++j) {
        const int idx = tid * 2 + j;             // 1024 = 16*64
        const int row = idx >> 6, n = idx & 63;
        ni_s[row][n] = nbr[((r0 + row) & 511) * 64 + n];
    }
    __syncthreads();

    // ---- gather X rows into abuf (bf16 swizzled): 512 chunks, 1/thread ----
    {
        const int row = tid >> 5, c = tid & 31;
        const size_t arow = (size_t)b * Vc + pps[row];
        uint4 d = *(const uint4*)(Xbf + arow * 256 + c * 8);
        *(uint4*)&abuf[row * 256 + ((c ^ row) * 8)] = d;
    }
    __syncthreads();

    // ---- ds GEMM: avF/abuf = Xg @ ds_W + ds_b ----
    {
        const unsigned short* Wt = Wm;           // slot 0
        f32x4 acc[2]; acc[0] = zero; acc[1] = zero;
        const unsigned short* wb = Wt + (size_t)(cb + ln) * 256 + quad * 8;
        #pragma unroll
        for (int ks = 0; ks < 8; ++ks) {
            bf16x8 A = *(const bf16x8*)&abuf[hsw_chunk(ln, ks, quad)];
            #pragma unroll
            for (int ct = 0; ct < 2; ++ct) {
                bf16x8 Bv = *(const bf16x8*)(wb + (size_t)ct * 16 * 256 + ks * 32);
                acc[ct] = __builtin_amdgcn_mfma_f32_16x16x32_bf16(A, Bv, acc[ct], 0, 0, 0);
            }
        }
        __syncthreads();   // all X reads done before abuf overwrite
        #pragma unroll
        for (int ct = 0; ct < 2; ++ct) {
            const int col = cb + ct * 16 + ln;
            const float bb = ds_b[col];
            #pragma unroll
            for (int r = 0; r < 4; ++r) {
                const int row = quad * 4 + r;
                float v = acc[ct][r] + bb;
                avF[row][col] = v;
                abuf[hsw_elem(row, col)] = f2bf(v);
            }
        }
    }
    __syncthreads();

    // ==================== transformer layers ====================
    for (int l = 0; l < Lc; ++l) {
        const unsigned short* kvb = keys + (((size_t)l * Bc + b) * Vc) * 256;
        const unsigned short* vvb = vals + (((size_t)l * Bc + b) * Vc) * 256;

        // ---- attention + LN1: wave w owns rows w*2, w*2+1 ----
        #pragma unroll
        for (int rr = 0; rr < 2; ++rr) {
            const int row = w * 2 + rr;
            const int p = (r0 + row) & 511;
            const int n = lane;
            for (int h = 0; h < 8; ++h) {
                // q into regs (broadcast LDS reads)
                float q[32];
                #pragma unroll
                for (int j = 0; j < 8; ++j) {
                    float4 t4 = *(const float4*)&avF[row][h * 32 + j * 4];
                    q[j * 4 + 0] = t4.x; q[j * 4 + 1] = t4.y;
                    q[j * 4 + 2] = t4.z; q[j * 4 + 3] = t4.w;
                }
                // score
                const int vi = ni_s[row][n];
                const unsigned short* kp = kvb + (size_t)vi * 256 + h * 32;
                float s = 0.f;
                #pragma unroll
                for (int j = 0; j < 4; ++j) {
                    uint4 u = *(const uint4*)(kp + j * 8);
                    s += q[j * 8 + 0] * bflo(u.x) + q[j * 8 + 1] * bfhi(u.x);
                    s += q[j * 8 + 2] * bflo(u.y) + q[j * 8 + 3] * bfhi(u.y);
                    s += q[j * 8 + 4] * bflo(u.z) + q[j * 8 + 5] * bfhi(u.z);
                    s += q[j * 8 + 6] * bflo(u.w) + q[j * 8 + 7] * bfhi(u.w);
                }
                s = (s - mask[p * 64 + n]) * 0.17677669529663689f;
                float mx = s;
                #pragma unroll
                for (int off = 32; off >= 1; off >>= 1) mx = fmaxf(mx, __shfl_xor(mx, off));
                float e = expf(s - mx);
                float sum = e;
                #pragma unroll
                for (int off = 32; off >= 1; off >>= 1) sum += __shfl_xor(sum, off);
                wtsb[w][n] = e / sum;
                // PV vectorized (same wave)
                const int nb4 = n >> 2, cg8 = (n & 3) * 8;
                float a[8];
                #pragma unroll
                for (int j = 0; j < 8; ++j) a[j] = 0.f;
                #pragma unroll
                for (int pass = 0; pass < 4; ++pass) {
                    const int nn = pass * 16 + nb4;
                    const float wgt = wtsb[w][nn];
                    const unsigned short* vp = vvb + (size_t)ni_s[row][nn] * 256 + h * 32 + cg8;
                    uint4 u = *(const uint4*)vp;
                    a[0] += wgt * bflo(u.x); a[1] += wgt * bfhi(u.x);
                    a[2] += wgt * bflo(u.y); a[3] += wgt * bfhi(u.y);
                    a[4] += wgt * bflo(u.z); a[5] += wgt * bfhi(u.z);
                    a[6] += wgt * bflo(u.w); a[7] += wgt * bfhi(u.w);
                }
                #pragma unroll
                for (int off = 4; off <= 32; off <<= 1)
                    #pragma unroll
                    for (int j = 0; j < 8; ++j)
                        a[j] += __shfl_xor(a[j], off);
                if (nb4 == 0)
                    #pragma unroll
                    for (int j = 0; j < 8; ++j)
                        attF[row][h * 32 + cg8 + j] = a[j];
            }
            // LN1 for this row (in-wave; attF[row] written by this wave)
            {
                const int c0 = lane * 4;
                float x[4];
                float sl = 0.f, ql = 0.f;
                #pragma unroll
                for (int j = 0; j < 4; ++j) {
                    x[j] = avF[row][c0 + j] + attF[row][c0 + j];
                    sl += x[j]; ql += x[j] * x[j];
                }
                #pragma unroll
                for (int off = 32; off >= 1; off >>= 1) {
                    sl += __shfl_xor(sl, off);
                    ql += __shfl_xor(ql, off);
                }
                const float mu = sl * (1.0f / 256.0f);
                const float var = ql * (1.0f / 256.0f) - mu * mu;
                const float rstd = 1.0f / sqrtf(fmaxf(var, 0.f) + 1e-5f);
                #pragma unroll
                for (int j = 0; j < 4; ++j) {
                    const int col = c0 + j;
                    float o = (x[j] - mu) * rstd * ln1_g[l * 256 + col] + ln1_b[l * 256 + col];
                    avF[row][col] = o;
                    abuf[hsw_elem(row, col)] = f2bf(o);
                }
            }
        }
        __syncthreads();

        // ---- ff stage A: T1 = relu(abuf @ W1 + b1) -> hbuf ----
        {
            const unsigned short* W1 = Wm + (size_t)(1 + l) * 65536;
            f32x4 acc[2]; acc[0] = zero; acc[1] = zero;
            const unsigned short* wb = W1 + (size_t)(cb + ln) * 256 + quad * 8;
            #pragma unroll
            for (int ks = 0; ks < 8; ++ks) {
                bf16x8 A = *(const bf16x8*)&abuf[hsw_chunk(ln, ks, quad)];
                #pragma unroll
                for (int ct = 0; ct < 2; ++ct) {
                    bf16x8 Bv = *(const bf16x8*)(wb + (size_t)ct * 16 * 256 + ks * 32);
                    acc[ct] = __builtin_amdgcn_mfma_f32_16x16x32_bf16(A, Bv, acc[ct], 0, 0, 0);
                }
            }
            #pragma unroll
            for (int ct = 0; ct < 2; ++ct) {
                const int col = cb + ct * 16 + ln;
                const float bb = ff_b1[l * 256 + col];
                #pragma unroll
                for (int r = 0; r < 4; ++r) {
                    const int row = quad * 4 + r;
                    hbuf[hsw_elem(row, col)] = f2bf(fmaxf(acc[ct][r] + bb, 0.f));
                }
            }
        }
        __syncthreads();

        // ---- ff stage B + residual + LN2 ----
        {
            const unsigned short* W2 = Wm + (size_t)(3 + l) * 65536;
            f32x4 acc[2]; acc[0] = zero; acc[1] = zero;
            const unsigned short* wb = W2 + (size_t)(cb + ln) * 256 + quad * 8;
            #pragma unroll
            for (int ks = 0; ks < 8; ++ks) {
                bf16x8 A = *(const bf16x8*)&hbuf[hsw_chunk(ln, ks, quad)];
                #pragma unroll
                for (int ct = 0; ct < 2; ++ct) {
                    bf16x8 Bv = *(const bf16x8*)(wb + (size_t)ct * 16 * 256 + ks * 32);
                    acc[ct] = __builtin_amdgcn_mfma_f32_16x16x32_bf16(A, Bv, acc[ct], 0, 0, 0);
                }
            }
            float vv[2][4];
            #pragma unroll
            for (int ct = 0; ct < 2; ++ct) {
                const int col = cb + ct * 16 + ln;
                const float bb = ff_b2[l * 256 + col];
                #pragma unroll
                for (int r = 0; r < 4; ++r) {
                    const int row = quad * 4 + r;
                    vv[ct][r] = acc[ct][r] + bb + avF[row][col];
                }
            }
            #pragma unroll
            for (int r = 0; r < 4; ++r) {
                float sl = vv[0][r] + vv[1][r];
                float ql = vv[0][r] * vv[0][r] + vv[1][r] * vv[1][r];
                #pragma unroll
                for (int off = 8; off >= 1; off >>= 1) {
                    sl += __shfl_xor(sl, off);
                    ql += __shfl_xor(ql, off);
                }
                if (ln == 0) {
                    const int row = quad * 4 + r;
                    psum[row][w] = sl; psq[row][w] = ql;
                }
            }
            __syncthreads();
            #pragma unroll
            for (int r = 0; r < 4; ++r) {
                const int row = quad * 4 + r;
                float sl = 0.f, ql = 0.f;
                #pragma unroll
                for (int j = 0; j < 8; ++j) { sl += psum[row][j]; ql += psq[row][j]; }
                const float mu = sl * (1.0f / 256.0f);
                const float var = ql * (1.0f / 256.0f) - mu * mu;
                const float rstd = 1.0f / sqrtf(fmaxf(var, 0.f) + 1e-5f);
                #pragma unroll
                for (int ct = 0; ct < 2; ++ct) {
                    const int col = cb + ct * 16 + ln;
                    float o = (vv[ct][r] - mu) * rstd * ln2_g[l * 256 + col] + ln2_b[l * 256 + col];
                    avF[row][col] = o;
                    abuf[hsw_elem(row, col)] = f2bf(o);
                }
            }
        }
        __syncthreads();
    }

    // ==================== decoder + loss ====================
    // stage 1: h1 = relu(abuf @ deW1 + b1) -> hbuf
    {
        const unsigned short* W1 = Wm + (size_t)5 * 65536;
        f32x4 acc[2]; acc[0] = zero; acc[1] = zero;
        const unsigned short* wb = W1 + (size_t)(cb + ln) * 256 + quad * 8;
        #pragma unroll
        for (int ks = 0; ks < 8; ++ks) {
            bf16x8 A = *(const bf16x8*)&abuf[hsw_chunk(ln, ks, quad)];
            #pragma unroll
            for (int ct = 0; ct < 2; ++ct) {
                bf16x8 Bv = *(const bf16x8*)(wb + (size_t)ct * 16 * 256 + ks * 32);
                acc[ct] = __builtin_amdgcn_mfma_f32_16x16x32_bf16(A, Bv, acc[ct], 0, 0, 0);
            }
        }
        #pragma unroll
        for (int ct = 0; ct < 2; ++ct) {
            const int col = cb + ct * 16 + ln;
            const float bb = de_b1[col];
            #pragma unroll
            for (int r = 0; r < 4; ++r) {
                const int row = quad * 4 + r;
                hbuf[hsw_elem(row, col)] = f2bf(fmaxf(acc[ct][r] + bb, 0.f));
            }
        }
    }
    __syncthreads();

    // stage 2: h2 = relu(hbuf @ deW2 + b2) -> hbuf (barrier-separated)
    {
        const unsigned short* W2 = Wm + (size_t)6 * 65536;
        f32x4 acc[2]; acc[0] = zero; acc[1] = zero;
        const unsigned short* wb = W2 + (size_t)(cb + ln) * 256 + quad * 8;
        #pragma unroll
        for (int ks = 0; ks < 8; ++ks) {
            bf16x8 A = *(const bf16x8*)&hbuf[hsw_chunk(ln, ks, quad)];
            #pragma unroll
            for (int ct = 0; ct < 2; ++ct) {
                bf16x8 Bv = *(const bf16x8*)(wb + (size_t)ct * 16 * 256 + ks * 32);
                acc[ct] = __builtin_amdgcn_mfma_f32_16x16x32_bf16(A, Bv, acc[ct], 0, 0, 0);
            }
        }
        __syncthreads();
        #pragma unroll
        for (int ct = 0; ct < 2; ++ct) {
            const int col = cb + ct * 16 + ln;
            const float bb = de_b2[col];
            #pragma unroll
            for (int r = 0; r < 4; ++r) {
                const int row = quad * 4 + r;
                hbuf[hsw_elem(row, col)] = f2bf(fmaxf(acc[ct][r] + bb, 0.f));
            }
        }
    }
    __syncthreads();

    // stage 3: logits (128 cols; wave w -> cols w*16..+15) + loss
    {
        const unsigned short* W3 = Wm + (size_t)7 * 65536;
        const int cb3 = w * 16;
        f32x4 a3 = zero;
        const unsigned short* wb = W3 + (size_t)(cb3 + ln) * 256 + quad * 8;
        #pragma unroll
        for (int ks = 0; ks < 8; ++ks) {
            bf16x8 A = *(const bf16x8*)&hbuf[hsw_chunk(ln, ks, quad)];
            bf16x8 Bv = *(const bf16x8*)(wb + ks * 32);
            a3 = __builtin_amdgcn_mfma_f32_16x16x32_bf16(A, Bv, a3, 0, 0, 0);
        }
        float lg[4];
        const float bb = de_b3[cb3 + ln];
        #pragma unroll
        for (int r = 0; r < 4; ++r) lg[r] = a3[r] + bb;

        // row-max partials (reuse psum/psq as pmax/pxt scratch)
        #pragma unroll
        for (int r = 0; r < 4; ++r) {
            float m = lg[r];
            #pragma unroll
            for (int off = 8; off >= 1; off >>= 1) m = fmaxf(m, __shfl_xor(m, off));
            if (ln == 0) psum[quad * 4 + r][w] = m;
        }
        __syncthreads();
        if (tid < 16) {
            float m = psum[tid][0];
            #pragma unroll
            for (int j = 1; j < 8; ++j) m = fmaxf(m, psum[tid][j]);
            rowmax[tid] = m;
            float tu = true_u[(size_t)b * Vc + pps[tid]];
            int t = (int)floorf(tu * 128.0f);
            tcol[tid] = t < 0 ? 0 : (t > 127 ? 127 : t);
        }
        __syncthreads();
        #pragma unroll
        for (int r = 0; r < 4; ++r) {
            const int row = quad * 4 + r;
            const float mx = rowmax[row];
            const int t = tcol[row];
            float e = expf(lg[r] - mx);
            float xt = ((cb3 + ln) == t) ? lg[r] : 0.f;
            #pragma unroll
            for (int off = 8; off >= 1; off >>= 1) {
                e += __shfl_xor(e, off);
                xt += __shfl_xor(xt, off);
            }
            if (ln == 0) { psum[row][w] = e; psq[row][w] = xt; }
        }
        __syncthreads();
        float contrib = 0.f;
        if (tid < 16) {
            float sum = 0.f, xt = 0.f;
            #pragma unroll
            for (int j = 0; j < 8; ++j) { sum += psum[tid][j]; xt += psq[tid][j]; }
            const float lp = logf(128.0f) + (xt - rowmax[tid]) - logf(sum);
            contrib = -lp;
        }
        if (w == 0) {
            #pragma unroll
            for (int off = 32; off >= 1; off >>= 1) contrib += __shfl_xor(contrib, off);
            if (lane == 0) atomicAdd(&outp[b], contrib);
        }
    }
}

// ---------------------------------------------------------------------------
extern "C" void kernel_launch(void* const* d_in, const int* in_sizes, int n_in,
                              void* d_out, int out_size, void* d_ws, size_t ws_size,
                              hipStream_t stream)
{
    (void)in_sizes; (void)n_in; (void)out_size; (void)ws_size;

    const float* encoded        = (const float*)d_in[0];
    const float* true_u         = (const float*)d_in[1];
    const float* attn_mask      = (const float*)d_in[2];
    const int*   pred_points    = (const int*)d_in[3];
    const int*   neighbor_index = (const int*)d_in[4];
    const float* kW1 = (const float*)d_in[5];
    const float* kb1 = (const float*)d_in[6];
    const float* kW2 = (const float*)d_in[7];
    const float* kb2 = (const float*)d_in[8];
    const float* kW3 = (const float*)d_in[9];
    const float* kb3 = (const float*)d_in[10];
    const float* vW1 = (const float*)d_in[11];
    const float* vb1 = (const float*)d_in[12];
    const float* vW2 = (const float*)d_in[13];
    const float* vb2 = (const float*)d_in[14];
    const float* vW3 = (const float*)d_in[15];
    const float* vb3 = (const float*)d_in[16];
    const float* ds_W  = (const float*)d_in[17];
    const float* ds_b  = (const float*)d_in[18];
    const float* ln1_g = (const float*)d_in[19];
    const float* ln1_b = (const float*)d_in[20];
    const float* ff_W1 = (const float*)d_in[21];
    const float* ff_b1 = (const float*)d_in[22];
    const float* ff_W2 = (const float*)d_in[23];
    const float* ff_b2 = (const float*)d_in[24];
    const float* ln2_g = (const float*)d_in[25];
    const float* ln2_b = (const float*)d_in[26];
    const float* de_W1 = (const float*)d_in[27];
    const float* de_b1 = (const float*)d_in[28];
    const float* de_W2 = (const float*)d_in[29];
    const float* de_b2 = (const float*)d_in[30];
    const float* de_W3 = (const float*)d_in[31];
    const float* de_b3 = (const float*)d_in[32];

    float* out = (float*)d_out;

    // workspace layout
    constexpr size_t KV_ELEMS = (size_t)Lc * Bc * Hc * Vc * 32;  // 8,388,608
    unsigned short* keys = (unsigned short*)d_ws;            // bf16 [l][b][v][256]
    unsigned short* vals = keys + KV_ELEMS;
    unsigned short* Xbf  = vals + KV_ELEMS;                  // 16384 x 256 bf16
    unsigned short* W1t  = Xbf + (size_t)ROWS_KV * 256;      // 32 nets x [256][256]
    unsigned short* W2t  = W1t + (size_t)32 * 65536;
    unsigned short* W3t  = W2t + (size_t)32 * 65536;         // 32 nets x [32][256]
    unsigned short* Wm   = W3t + (size_t)32 * 8192;          // 8 slots x 65536

    (void)hipMemsetAsync(out, 0, Bc * sizeof(float), stream);

    // prep
    conv_x_kernel<<<dim3(ROWS_KV * 256 / 4 / 256), 256, 0, stream>>>(encoded, Xbf);
    transpose_all_kernel<<<dim3(8, 8, 104), 256, 0, stream>>>(
        kW1, vW1, kW2, vW2, kW3, vW3,
        ds_W, ff_W1, ff_W2, de_W1, de_W2, de_W3,
        W1t, W2t, W3t, Wm);

    // KV MLPs v7b: 16 rg x 16 (l,h) x {k,v}
    kv_mfma_kernel<<<dim3(16, 16, 2), 512, 0, stream>>>(
        Xbf, true_u, W1t, W2t, W3t, kW1, vW1,
        kb1, kb2, kb3, vb1, vb2, vb3, keys, vals);

    // fused tail: everything after kv in ONE kernel
    decoder_kernel<<<dim3(ROWS_AT / 16), 512, 0, stream>>>(
        Xbf, true_u, keys, vals, neighbor_index, attn_mask, pred_points, Wm,
        ds_b, ln1_g, ln1_b, ff_b1, ff_b2, ln2_g, ln2_b,
        de_b1, de_b2, de_b3, out);
}